// Round 5
// baseline (805.903 us; speedup 1.0000x reference)
//
#include <hip/hip_runtime.h>
#include <hip/hip_bf16.h>
#include <math.h>

#define CH 128
#define BSHIFT 5   // 32 nodes per bucket

__device__ __forceinline__ float seluf(float x) {
    const float scale = 1.0507009873554804934193349852946f;
    const float alpha = 1.6732632423543772848170429916717f;
    return x > 0.0f ? scale * x : scale * alpha * (__expf(x) - 1.0f);
}

__device__ __forceinline__ float lrelu(float x) {
    return x > 0.0f ? x : 0.2f * x;
}

// ---- CSR build -------------------------------------------------------------

__global__ void k_hist(const int* __restrict__ ei, int* __restrict__ counts, int E) {
    int stride = gridDim.x * blockDim.x;
    for (int j = blockIdx.x * blockDim.x + threadIdx.x; j < E; j += stride)
        atomicAdd(&counts[ei[E + j]], 1);   // row 1 of edge_index = dst
}

// rowptr scan; also emits bucket staging offsets bstart[b] = rowptr[32b]-32b.
__global__ __launch_bounds__(1024) void k_scan(const int* __restrict__ counts,
                                               int* __restrict__ rowptr,
                                               int* __restrict__ bstart, int n) {
    const int T = 1024;
    int t = threadIdx.x;
    int per = (n + T - 1) / T;
    int beg = t * per;
    int end = beg + per; if (end > n) end = n; if (beg > n) beg = n;
    int sum = 0;
    for (int i = beg; i < end; ++i) sum += counts[i] + 1;   // +1 self loop
    __shared__ int sbuf[T];
    sbuf[t] = sum;
    __syncthreads();
    for (int off = 1; off < T; off <<= 1) {
        int v = (t >= off) ? sbuf[t - off] : 0;
        __syncthreads();
        sbuf[t] += v;
        __syncthreads();
    }
    int run = sbuf[t] - sum;     // exclusive prefix
    for (int i = beg; i < end; ++i) {
        rowptr[i] = run;
        if ((i & ((1 << BSHIFT) - 1)) == 0) bstart[i >> BSHIFT] = run - i;
        run += counts[i] + 1;
    }
    if (t == T - 1) rowptr[n] = run;
}

// Pass 1: append packed (dst,src) records into dst-range buckets (seq. writes).
__global__ void k_bucket(const int* __restrict__ ei, const int* __restrict__ bstart,
                         int* __restrict__ bfill, unsigned long long* __restrict__ staged,
                         int E) {
    int stride = gridDim.x * blockDim.x;
    for (int j = blockIdx.x * blockDim.x + threadIdx.x; j < E; j += stride) {
        int s = ei[j], d = ei[E + j];
        int b = d >> BSHIFT;
        int pos = bstart[b] + atomicAdd(&bfill[b], 1);
        staged[pos] = ((unsigned long long)(unsigned)d << 32) | (unsigned)s;
    }
}

// Pass 2: coalesced read of staged records; csr stores hit a small L2 window.
__global__ void k_scatter2(const unsigned long long* __restrict__ staged,
                           const int* __restrict__ rowptr, int* __restrict__ fill,
                           int* __restrict__ csr, int n, int E) {
    int stride = gridDim.x * blockDim.x;
    int t0 = blockIdx.x * blockDim.x + threadIdx.x;
    for (int i = t0; i < n; i += stride) csr[rowptr[i]] = i;          // self loop slot
    for (int j = t0; j < E; j += stride) {
        unsigned long long v = staged[j];
        int d = (int)(v >> 32), s = (int)(v & 0xffffffffu);
        int pos = rowptr[d] + 1 + atomicAdd(&fill[d], 1);
        csr[pos] = s;
    }
}

// ---- GEMM v2: h = x@W (bf16 out), fused attention dots ---------------------

__global__ __launch_bounds__(256) void k_gemm2(
    const float* __restrict__ x, const float* __restrict__ W,
    const float* __restrict__ a_s, const float* __restrict__ a_d,
    __hip_bfloat16* __restrict__ hb, float* __restrict__ as_o,
    float* __restrict__ ad_o, int n) {
    __shared__ float Wl[CH * CH];
    const int tid = threadIdx.x;
    for (int i = tid; i < CH * CH; i += 256) {
        int k = i >> 7, c = i & 127;
        Wl[((k >> 2) << 9) + (c << 2) + (k & 3)] = W[i];
    }
    __syncthreads();
    const int lane = tid & 63;
    const int wid = __builtin_amdgcn_readfirstlane(tid >> 6);
    const float as0 = a_s[lane], as1 = a_s[lane + 64];
    const float ad0 = a_d[lane], ad1 = a_d[lane + 64];

    int r0 = blockIdx.x * 32 + wid * 8;
    if (r0 >= n) return;

    int rr[8];
#pragma unroll
    for (int j = 0; j < 8; ++j) rr[j] = (r0 + j < n) ? (r0 + j) : (n - 1);

    float acc0[8], acc1[8];
#pragma unroll
    for (int j = 0; j < 8; ++j) { acc0[j] = 0.f; acc1[j] = 0.f; }

#pragma unroll 4
    for (int k4 = 0; k4 < 32; ++k4) {
        float4 xv[8];
#pragma unroll
        for (int j = 0; j < 8; ++j)
            xv[j] = ((const float4*)(x + (size_t)rr[j] * CH))[k4];
        float4 w0 = *(const float4*)(Wl + (k4 << 9) + (lane << 2));
        float4 w1 = *(const float4*)(Wl + (k4 << 9) + ((lane + 64) << 2));
#pragma unroll
        for (int j = 0; j < 8; ++j) {
            acc0[j] += xv[j].x * w0.x + xv[j].y * w0.y + xv[j].z * w0.z + xv[j].w * w0.w;
            acc1[j] += xv[j].x * w1.x + xv[j].y * w1.y + xv[j].z * w1.z + xv[j].w * w1.w;
        }
    }

#pragma unroll
    for (int j = 0; j < 8; ++j) {
        int r = r0 + j;
        if (r >= n) break;
        float pa = acc0[j] * as0 + acc1[j] * as1;
        float pd = acc0[j] * ad0 + acc1[j] * ad1;
#pragma unroll
        for (int o = 32; o > 0; o >>= 1) {
            pa += __shfl_xor(pa, o);
            pd += __shfl_xor(pd, o);
        }
        hb[(size_t)r * CH + lane] = __float2bfloat16(acc0[j]);
        hb[(size_t)r * CH + 64 + lane] = __float2bfloat16(acc1[j]);
        if (lane == 0) { as_o[r] = pa; ad_o[r] = pd; }
    }
}

// ---- fused softmax + aggregation: one wave per node ------------------------

__global__ __launch_bounds__(256) void k_fused_agg(
    const int* __restrict__ rowptr, const int* __restrict__ csr,
    const float* __restrict__ as_v, const float* __restrict__ ad_v,
    float* __restrict__ wedge, const __hip_bfloat16* __restrict__ hb,
    const float* __restrict__ bias, float* __restrict__ out, int n) {
    int gw = (int)((blockIdx.x * (size_t)blockDim.x + threadIdx.x) >> 6);
    int lane = threadIdx.x & 63;
    if (gw >= n) return;
    int beg = rowptr[gw], end = rowptr[gw + 1];
    float adi = ad_v[gw];

    // Phase A: scores + max (coalesced wedge writes)
    float m = -1e30f;
    for (int p = beg + lane; p < end; p += 64) {
        float e = lrelu(as_v[csr[p]] + adi);
        wedge[p] = e;
        m = fmaxf(m, e);
    }
#pragma unroll
    for (int o = 32; o > 0; o >>= 1) m = fmaxf(m, __shfl_xor(m, o));

    // Phase B: exp + denom
    float s = 0.f;
    for (int p = beg + lane; p < end; p += 64) {
        float wv = __expf(wedge[p] - m);
        wedge[p] = wv;
        s += wv;
    }
#pragma unroll
    for (int o = 32; o > 0; o >>= 1) s += __shfl_xor(s, o);
    float inv = 1.0f / s;

    // Phase C: bf16 gather-accumulate, 4 edges per iteration
    const int quarter = lane >> 4;     // edge sub-slot 0..3
    const int c8 = lane & 15;          // 8-channel block
    float acc[8];
#pragma unroll
    for (int k = 0; k < 8; ++k) acc[k] = 0.f;
    for (int p = beg; p < end; p += 4) {
        int pp = p + quarter;
        float wv; int src;
        if (pp < end) { wv = wedge[pp]; src = csr[pp]; }
        else { wv = 0.f; src = 0; }
        uint4 hv = ((const uint4*)hb)[(size_t)src * 16 + c8];
        acc[0] += wv * __uint_as_float(hv.x << 16);
        acc[1] += wv * __uint_as_float(hv.x & 0xffff0000u);
        acc[2] += wv * __uint_as_float(hv.y << 16);
        acc[3] += wv * __uint_as_float(hv.y & 0xffff0000u);
        acc[4] += wv * __uint_as_float(hv.z << 16);
        acc[5] += wv * __uint_as_float(hv.z & 0xffff0000u);
        acc[6] += wv * __uint_as_float(hv.w << 16);
        acc[7] += wv * __uint_as_float(hv.w & 0xffff0000u);
    }
#pragma unroll
    for (int k = 0; k < 8; ++k) {
        acc[k] += __shfl_xor(acc[k], 16);
        acc[k] += __shfl_xor(acc[k], 32);
    }
    if (quarter == 0) {
        const float4 bv0 = ((const float4*)bias)[c8 * 2];
        const float4 bv1 = ((const float4*)bias)[c8 * 2 + 1];
        float4 o0, o1;
        o0.x = seluf(acc[0] * inv + bv0.x);
        o0.y = seluf(acc[1] * inv + bv0.y);
        o0.z = seluf(acc[2] * inv + bv0.z);
        o0.w = seluf(acc[3] * inv + bv0.w);
        o1.x = seluf(acc[4] * inv + bv1.x);
        o1.y = seluf(acc[5] * inv + bv1.y);
        o1.z = seluf(acc[6] * inv + bv1.z);
        o1.w = seluf(acc[7] * inv + bv1.w);
        ((float4*)out)[(size_t)gw * 32 + c8 * 2] = o0;
        ((float4*)out)[(size_t)gw * 32 + c8 * 2 + 1] = o1;
    }
}

// ---- global mean pool (batch is sorted) ------------------------------------

__device__ int lower_bound_dev(const int* a, int n, int key) {
    int lo = 0, hi = n;
    while (lo < hi) {
        int mid = (lo + hi) >> 1;
        if (a[mid] < key) lo = mid + 1; else hi = mid;
    }
    return lo;
}

__global__ __launch_bounds__(256) void k_pool(const float* __restrict__ x,
                                              const int* __restrict__ batchv,
                                              float* __restrict__ outp, int n) {
    int g = blockIdx.x;
    int lo = lower_bound_dev(batchv, n, g);
    int hi = lower_bound_dev(batchv, n, g + 1);
    int lane = threadIdx.x & 63, wv = threadIdx.x >> 6;
    float sx = 0.f, sy = 0.f;
    for (int i = lo + wv; i < hi; i += 4) {
        float2 v = ((const float2*)x)[(size_t)i * 64 + lane];
        sx += v.x;
        sy += v.y;
    }
    __shared__ float2 red[4][64];
    red[wv][lane] = make_float2(sx, sy);
    __syncthreads();
    if (wv == 0) {
        float2 a = red[0][lane], b = red[1][lane], c = red[2][lane], d = red[3][lane];
        int cntv = hi - lo; if (cntv < 1) cntv = 1;
        float inv = 1.0f / (float)cntv;
        outp[(size_t)g * CH + 2 * lane] = (a.x + b.x + c.x + d.x) * inv;
        outp[(size_t)g * CH + 2 * lane + 1] = (a.y + b.y + c.y + d.y) * inv;
    }
}

// ---- orchestration ---------------------------------------------------------

extern "C" void kernel_launch(void* const* d_in, const int* in_sizes, int n_in,
                              void* d_out, int out_size, void* d_ws, size_t ws_size,
                              hipStream_t stream) {
    const float* u   = (const float*)d_in[0];
    const float* W1  = (const float*)d_in[1];
    const float* as1 = (const float*)d_in[2];
    const float* ad1 = (const float*)d_in[3];
    const float* b1  = (const float*)d_in[4];
    const float* W2  = (const float*)d_in[5];
    const float* as2 = (const float*)d_in[6];
    const float* ad2 = (const float*)d_in[7];
    const float* b2  = (const float*)d_in[8];
    const int* ei    = (const int*)d_in[9];
    const int* batchv= (const int*)d_in[10];

    const int N = in_sizes[0] / CH;
    const int E = in_sizes[9] / 2;
    const int M = E + N;
    const int NB = (N + (1 << BSHIFT) - 1) >> BSHIFT;

    char* p = (char*)d_ws;
    auto alloc = [&](size_t bytes) {
        char* r = p;
        p += (bytes + 255) & ~(size_t)255;
        return r;
    };
    int*   counts = (int*)alloc((size_t)N * 4);
    int*   fill   = (int*)alloc((size_t)N * 4);
    int*   bfill  = (int*)alloc((size_t)NB * 4);
    size_t zbytes = (size_t)(p - (char*)d_ws);      // zero counts+fill+bfill
    int*   rowptr = (int*)alloc((size_t)(N + 1) * 4);
    int*   bstart = (int*)alloc((size_t)(NB + 1) * 4);
    int*   csr    = (int*)alloc((size_t)M * 4);
    float* wedge  = (float*)alloc((size_t)M * 4);
    float* asv    = (float*)alloc((size_t)N * 4);
    float* adv    = (float*)alloc((size_t)N * 4);
    // staged aliases hbuf: staged is fully consumed by k_scatter2 before the
    // first k_gemm2 writes hbuf.
    size_t hbytes = (size_t)N * CH * 2;
    size_t sbytes = (size_t)E * 8;
    char*  hs     = alloc(hbytes > sbytes ? hbytes : sbytes);
    __hip_bfloat16* hbuf = (__hip_bfloat16*)hs;
    unsigned long long* staged = (unsigned long long*)hs;
    float* x2     = (float*)alloc((size_t)N * CH * 4);

    hipMemsetAsync(d_ws, 0, zbytes, stream);

    k_hist<<<2048, 256, 0, stream>>>(ei, counts, E);
    k_scan<<<1, 1024, 0, stream>>>(counts, rowptr, bstart, N);
    k_bucket<<<2048, 256, 0, stream>>>(ei, bstart, bfill, staged, E);
    k_scatter2<<<2048, 256, 0, stream>>>(staged, rowptr, fill, csr, N, E);

    const int gblocks = (N + 31) / 32;

    // layer 1
    k_gemm2<<<gblocks, 256, 0, stream>>>(u, W1, as1, ad1, hbuf, asv, adv, N);
    k_fused_agg<<<(N * 64 + 255) / 256, 256, 0, stream>>>(rowptr, csr, asv, adv, wedge, hbuf, b1, x2, N);

    // layer 2
    k_gemm2<<<gblocks, 256, 0, stream>>>(x2, W2, as2, ad2, hbuf, asv, adv, N);
    k_fused_agg<<<(N * 64 + 255) / 256, 256, 0, stream>>>(rowptr, csr, asv, adv, wedge, hbuf, b2, x2, N);

    k_pool<<<64, 256, 0, stream>>>(x2, batchv, (float*)d_out, N);
}

// Round 6
// 546.550 us; speedup vs baseline: 1.4745x; 1.4745x over previous
//
#include <hip/hip_runtime.h>
#include <hip/hip_bf16.h>
#include <math.h>

#define CH 128
#define PSHIFT 9              // 512 nodes per partition
#define PSIZE (1 << PSHIFT)
#define CHUNK 2048            // edges per block in k_part
#define EPT 8                 // edges per thread (256 * 8 = 2048)
#define MAXP 128              // max partitions (N <= 65536)

__device__ __forceinline__ float seluf(float x) {
    const float scale = 1.0507009873554804934193349852946f;
    const float alpha = 1.6732632423543772848170429916717f;
    return x > 0.0f ? scale * x : scale * alpha * (__expf(x) - 1.0f);
}

__device__ __forceinline__ float lrelu(float x) {
    return x > 0.0f ? x : 0.2f * x;
}

// ---- CSR build -------------------------------------------------------------

__global__ void k_hist(const int* __restrict__ ei, int* __restrict__ counts, int E) {
    int stride = gridDim.x * blockDim.x;
    for (int j = blockIdx.x * blockDim.x + threadIdx.x; j < E; j += stride)
        atomicAdd(&counts[ei[E + j]], 1);   // row 1 of edge_index = dst
}

// rowptr scan; also emits partition staging offsets pstart[p]=rowptr[512p]-512p.
__global__ __launch_bounds__(1024) void k_scan(const int* __restrict__ counts,
                                               int* __restrict__ rowptr,
                                               int* __restrict__ pstart, int n) {
    const int T = 1024;
    int t = threadIdx.x;
    int per = (n + T - 1) / T;
    int beg = t * per;
    int end = beg + per; if (end > n) end = n; if (beg > n) beg = n;
    int sum = 0;
    for (int i = beg; i < end; ++i) sum += counts[i] + 1;   // +1 self loop
    __shared__ int sbuf[T];
    sbuf[t] = sum;
    __syncthreads();
    for (int off = 1; off < T; off <<= 1) {
        int v = (t >= off) ? sbuf[t - off] : 0;
        __syncthreads();
        sbuf[t] += v;
        __syncthreads();
    }
    int run = sbuf[t] - sum;     // exclusive prefix
    for (int i = beg; i < end; ++i) {
        rowptr[i] = run;
        if ((i & (PSIZE - 1)) == 0) pstart[i >> PSHIFT] = run - i;
        run += counts[i] + 1;
    }
    if (t == T - 1) {
        rowptr[n] = run;
        pstart[(n + PSIZE - 1) >> PSHIFT] = run - n;   // == E
    }
}

// Pass A: block-local binning. LDS histogram -> local ranks; one global atomic
// per (block, partition) reserves a contiguous span; bursts written by one CU.
__global__ __launch_bounds__(256) void k_part(const int* __restrict__ ei,
                                              const int* __restrict__ pstart,
                                              int* __restrict__ pfill,
                                              unsigned long long* __restrict__ staged,
                                              int E, int NP) {
    __shared__ int hist[MAXP];
    __shared__ int base[MAXP];
    const int tid = threadIdx.x;
    const int j0 = blockIdx.x * CHUNK;
    for (int i = tid; i < NP; i += 256) hist[i] = 0;
    __syncthreads();
    int part[EPT], rank[EPT];
    unsigned long long rec[EPT];
#pragma unroll
    for (int e = 0; e < EPT; ++e) {
        int j = j0 + e * 256 + tid;
        part[e] = -1;
        if (j < E) {
            int s = ei[j], d = ei[E + j];
            part[e] = d >> PSHIFT;
            rec[e] = ((unsigned long long)(unsigned)d << 32) | (unsigned)s;
            rank[e] = atomicAdd(&hist[part[e]], 1);
        }
    }
    __syncthreads();
    for (int i = tid; i < NP; i += 256)
        base[i] = hist[i] ? atomicAdd(&pfill[i], hist[i]) : 0;
    __syncthreads();
#pragma unroll
    for (int e = 0; e < EPT; ++e)
        if (part[e] >= 0)
            staged[pstart[part[e]] + base[part[e]] + rank[e]] = rec[e];
}

// Pass B: one block per partition; fill counters in LDS; csr window (~67KB)
// written by a single CU -> write amp ~1.
__global__ __launch_bounds__(1024) void k_scatter3(
    const unsigned long long* __restrict__ staged, const int* __restrict__ rowptr,
    const int* __restrict__ pstart, int* __restrict__ csr, int n) {
    const int p = blockIdx.x;
    const int d0 = p << PSHIFT;
    const int d1 = min(n, d0 + PSIZE);
    __shared__ int lfill[PSIZE];
    const int tid = threadIdx.x;
    for (int i = tid; i < PSIZE; i += 1024) lfill[i] = 0;
    for (int i = d0 + tid; i < d1; i += 1024) csr[rowptr[i]] = i;   // self loops
    __syncthreads();
    const int rbeg = pstart[p], rend = pstart[p + 1];
    for (int r = rbeg + tid; r < rend; r += 1024) {
        unsigned long long v = staged[r];
        int d = (int)(v >> 32), s = (int)(v & 0xffffffffu);
        int pos = rowptr[d] + 1 + atomicAdd(&lfill[d - d0], 1);
        csr[pos] = s;
    }
}

// ---- GEMM v2: h = x@W (bf16 out), fused attention dots ---------------------

__global__ __launch_bounds__(256) void k_gemm2(
    const float* __restrict__ x, const float* __restrict__ W,
    const float* __restrict__ a_s, const float* __restrict__ a_d,
    __hip_bfloat16* __restrict__ hb, float* __restrict__ as_o,
    float* __restrict__ ad_o, int n) {
    __shared__ float Wl[CH * CH];
    const int tid = threadIdx.x;
    for (int i = tid; i < CH * CH; i += 256) {
        int k = i >> 7, c = i & 127;
        Wl[((k >> 2) << 9) + (c << 2) + (k & 3)] = W[i];
    }
    __syncthreads();
    const int lane = tid & 63;
    const int wid = __builtin_amdgcn_readfirstlane(tid >> 6);
    const float as0 = a_s[lane], as1 = a_s[lane + 64];
    const float ad0 = a_d[lane], ad1 = a_d[lane + 64];

    int r0 = blockIdx.x * 32 + wid * 8;
    if (r0 >= n) return;

    int rr[8];
#pragma unroll
    for (int j = 0; j < 8; ++j) rr[j] = (r0 + j < n) ? (r0 + j) : (n - 1);

    float acc0[8], acc1[8];
#pragma unroll
    for (int j = 0; j < 8; ++j) { acc0[j] = 0.f; acc1[j] = 0.f; }

#pragma unroll 4
    for (int k4 = 0; k4 < 32; ++k4) {
        float4 xv[8];
#pragma unroll
        for (int j = 0; j < 8; ++j)
            xv[j] = ((const float4*)(x + (size_t)rr[j] * CH))[k4];
        float4 w0 = *(const float4*)(Wl + (k4 << 9) + (lane << 2));
        float4 w1 = *(const float4*)(Wl + (k4 << 9) + ((lane + 64) << 2));
#pragma unroll
        for (int j = 0; j < 8; ++j) {
            acc0[j] += xv[j].x * w0.x + xv[j].y * w0.y + xv[j].z * w0.z + xv[j].w * w0.w;
            acc1[j] += xv[j].x * w1.x + xv[j].y * w1.y + xv[j].z * w1.z + xv[j].w * w1.w;
        }
    }

#pragma unroll
    for (int j = 0; j < 8; ++j) {
        int r = r0 + j;
        if (r >= n) break;
        float pa = acc0[j] * as0 + acc1[j] * as1;
        float pd = acc0[j] * ad0 + acc1[j] * ad1;
#pragma unroll
        for (int o = 32; o > 0; o >>= 1) {
            pa += __shfl_xor(pa, o);
            pd += __shfl_xor(pd, o);
        }
        hb[(size_t)r * CH + lane] = __float2bfloat16(acc0[j]);
        hb[(size_t)r * CH + 64 + lane] = __float2bfloat16(acc1[j]);
        if (lane == 0) { as_o[r] = pa; ad_o[r] = pd; }
    }
}

// ---- fused softmax + aggregation: one wave per node ------------------------

__global__ __launch_bounds__(256) void k_fused_agg(
    const int* __restrict__ rowptr, const int* __restrict__ csr,
    const float* __restrict__ as_v, const float* __restrict__ ad_v,
    float* __restrict__ wedge, const __hip_bfloat16* __restrict__ hb,
    const float* __restrict__ bias, float* __restrict__ out, int n) {
    int gw = (int)((blockIdx.x * (size_t)blockDim.x + threadIdx.x) >> 6);
    int lane = threadIdx.x & 63;
    if (gw >= n) return;
    int beg = rowptr[gw], end = rowptr[gw + 1];
    float adi = ad_v[gw];

    // Phase A: scores + max (coalesced wedge writes)
    float m = -1e30f;
    for (int p = beg + lane; p < end; p += 64) {
        float e = lrelu(as_v[csr[p]] + adi);
        wedge[p] = e;
        m = fmaxf(m, e);
    }
#pragma unroll
    for (int o = 32; o > 0; o >>= 1) m = fmaxf(m, __shfl_xor(m, o));

    // Phase B: exp + denom
    float s = 0.f;
    for (int p = beg + lane; p < end; p += 64) {
        float wv = __expf(wedge[p] - m);
        wedge[p] = wv;
        s += wv;
    }
#pragma unroll
    for (int o = 32; o > 0; o >>= 1) s += __shfl_xor(s, o);
    float inv = 1.0f / s;

    // Phase C: bf16 gather-accumulate, 4 edges per iteration
    const int quarter = lane >> 4;     // edge sub-slot 0..3
    const int c8 = lane & 15;          // 8-channel block
    float acc[8];
#pragma unroll
    for (int k = 0; k < 8; ++k) acc[k] = 0.f;
    for (int p = beg; p < end; p += 4) {
        int pp = p + quarter;
        float wv; int src;
        if (pp < end) { wv = wedge[pp]; src = csr[pp]; }
        else { wv = 0.f; src = 0; }
        uint4 hv = ((const uint4*)hb)[(size_t)src * 16 + c8];
        acc[0] += wv * __uint_as_float(hv.x << 16);
        acc[1] += wv * __uint_as_float(hv.x & 0xffff0000u);
        acc[2] += wv * __uint_as_float(hv.y << 16);
        acc[3] += wv * __uint_as_float(hv.y & 0xffff0000u);
        acc[4] += wv * __uint_as_float(hv.z << 16);
        acc[5] += wv * __uint_as_float(hv.z & 0xffff0000u);
        acc[6] += wv * __uint_as_float(hv.w << 16);
        acc[7] += wv * __uint_as_float(hv.w & 0xffff0000u);
    }
#pragma unroll
    for (int k = 0; k < 8; ++k) {
        acc[k] += __shfl_xor(acc[k], 16);
        acc[k] += __shfl_xor(acc[k], 32);
    }
    if (quarter == 0) {
        const float4 bv0 = ((const float4*)bias)[c8 * 2];
        const float4 bv1 = ((const float4*)bias)[c8 * 2 + 1];
        float4 o0, o1;
        o0.x = seluf(acc[0] * inv + bv0.x);
        o0.y = seluf(acc[1] * inv + bv0.y);
        o0.z = seluf(acc[2] * inv + bv0.z);
        o0.w = seluf(acc[3] * inv + bv0.w);
        o1.x = seluf(acc[4] * inv + bv1.x);
        o1.y = seluf(acc[5] * inv + bv1.y);
        o1.z = seluf(acc[6] * inv + bv1.z);
        o1.w = seluf(acc[7] * inv + bv1.w);
        ((float4*)out)[(size_t)gw * 32 + c8 * 2] = o0;
        ((float4*)out)[(size_t)gw * 32 + c8 * 2 + 1] = o1;
    }
}

// ---- global mean pool (batch is sorted) ------------------------------------

__device__ int lower_bound_dev(const int* a, int n, int key) {
    int lo = 0, hi = n;
    while (lo < hi) {
        int mid = (lo + hi) >> 1;
        if (a[mid] < key) lo = mid + 1; else hi = mid;
    }
    return lo;
}

__global__ __launch_bounds__(256) void k_pool(const float* __restrict__ x,
                                              const int* __restrict__ batchv,
                                              float* __restrict__ outp, int n) {
    int g = blockIdx.x;
    int lo = lower_bound_dev(batchv, n, g);
    int hi = lower_bound_dev(batchv, n, g + 1);
    int lane = threadIdx.x & 63, wv = threadIdx.x >> 6;
    float sx = 0.f, sy = 0.f;
    for (int i = lo + wv; i < hi; i += 4) {
        float2 v = ((const float2*)x)[(size_t)i * 64 + lane];
        sx += v.x;
        sy += v.y;
    }
    __shared__ float2 red[4][64];
    red[wv][lane] = make_float2(sx, sy);
    __syncthreads();
    if (wv == 0) {
        float2 a = red[0][lane], b = red[1][lane], c = red[2][lane], d = red[3][lane];
        int cntv = hi - lo; if (cntv < 1) cntv = 1;
        float inv = 1.0f / (float)cntv;
        outp[(size_t)g * CH + 2 * lane] = (a.x + b.x + c.x + d.x) * inv;
        outp[(size_t)g * CH + 2 * lane + 1] = (a.y + b.y + c.y + d.y) * inv;
    }
}

// ---- orchestration ---------------------------------------------------------

extern "C" void kernel_launch(void* const* d_in, const int* in_sizes, int n_in,
                              void* d_out, int out_size, void* d_ws, size_t ws_size,
                              hipStream_t stream) {
    const float* u   = (const float*)d_in[0];
    const float* W1  = (const float*)d_in[1];
    const float* as1 = (const float*)d_in[2];
    const float* ad1 = (const float*)d_in[3];
    const float* b1  = (const float*)d_in[4];
    const float* W2  = (const float*)d_in[5];
    const float* as2 = (const float*)d_in[6];
    const float* ad2 = (const float*)d_in[7];
    const float* b2  = (const float*)d_in[8];
    const int* ei    = (const int*)d_in[9];
    const int* batchv= (const int*)d_in[10];

    const int N = in_sizes[0] / CH;
    const int E = in_sizes[9] / 2;
    const int M = E + N;
    const int NP = (N + PSIZE - 1) >> PSHIFT;

    char* p = (char*)d_ws;
    auto alloc = [&](size_t bytes) {
        char* r = p;
        p += (bytes + 255) & ~(size_t)255;
        return r;
    };
    int*   counts = (int*)alloc((size_t)N * 4);
    int*   pfill  = (int*)alloc((size_t)NP * 4);
    size_t zbytes = (size_t)(p - (char*)d_ws);      // zero counts+pfill
    int*   rowptr = (int*)alloc((size_t)(N + 1) * 4);
    int*   pstart = (int*)alloc((size_t)(NP + 1) * 4);
    int*   csr    = (int*)alloc((size_t)M * 4);
    float* wedge  = (float*)alloc((size_t)M * 4);
    float* asv    = (float*)alloc((size_t)N * 4);
    float* adv    = (float*)alloc((size_t)N * 4);
    // staged aliases hbuf: staged is fully consumed by k_scatter3 before the
    // first k_gemm2 writes hbuf.
    size_t hbytes = (size_t)N * CH * 2;
    size_t sbytes = (size_t)E * 8;
    char*  hs     = alloc(hbytes > sbytes ? hbytes : sbytes);
    __hip_bfloat16* hbuf = (__hip_bfloat16*)hs;
    unsigned long long* staged = (unsigned long long*)hs;
    float* x2     = (float*)alloc((size_t)N * CH * 4);

    hipMemsetAsync(d_ws, 0, zbytes, stream);

    k_hist<<<2048, 256, 0, stream>>>(ei, counts, E);
    k_scan<<<1, 1024, 0, stream>>>(counts, rowptr, pstart, N);
    k_part<<<(E + CHUNK - 1) / CHUNK, 256, 0, stream>>>(ei, pstart, pfill, staged, E, NP);
    k_scatter3<<<NP, 1024, 0, stream>>>(staged, rowptr, pstart, csr, N);

    const int gblocks = (N + 31) / 32;

    // layer 1
    k_gemm2<<<gblocks, 256, 0, stream>>>(u, W1, as1, ad1, hbuf, asv, adv, N);
    k_fused_agg<<<(N * 64 + 255) / 256, 256, 0, stream>>>(rowptr, csr, asv, adv, wedge, hbuf, b1, x2, N);

    // layer 2
    k_gemm2<<<gblocks, 256, 0, stream>>>(x2, W2, as2, ad2, hbuf, asv, adv, N);
    k_fused_agg<<<(N * 64 + 255) / 256, 256, 0, stream>>>(rowptr, csr, asv, adv, wedge, hbuf, b2, x2, N);

    k_pool<<<64, 256, 0, stream>>>(x2, batchv, (float*)d_out, N);
}

// Round 7
// 440.852 us; speedup vs baseline: 1.8281x; 1.2398x over previous
//
#include <hip/hip_runtime.h>
#include <hip/hip_bf16.h>
#include <math.h>

#define CH 128
#define PSHIFT 9              // 512 nodes per partition
#define PSIZE (1 << PSHIFT)
#define CHUNK 2048            // edges per block in k_part
#define EPT 8                 // edges per thread (256 * 8 = 2048)
#define MAXP 128              // max partitions (N <= 65536)

typedef __attribute__((ext_vector_type(8))) short short8;
typedef __attribute__((ext_vector_type(4))) float f32x4;

__device__ __forceinline__ float seluf(float x) {
    const float scale = 1.0507009873554804934193349852946f;
    const float alpha = 1.6732632423543772848170429916717f;
    return x > 0.0f ? scale * x : scale * alpha * (__expf(x) - 1.0f);
}

__device__ __forceinline__ float lrelu(float x) {
    return x > 0.0f ? x : 0.2f * x;
}

__device__ __forceinline__ short bfc(float f) {
    union { __hip_bfloat16 b; short s; } u;
    u.b = __float2bfloat16(f);
    return u.s;
}

// ---- CSR build -------------------------------------------------------------

__global__ void k_hist(const int* __restrict__ ei, int* __restrict__ counts, int E) {
    int stride = gridDim.x * blockDim.x;
    for (int j = blockIdx.x * blockDim.x + threadIdx.x; j < E; j += stride)
        atomicAdd(&counts[ei[E + j]], 1);   // row 1 of edge_index = dst
}

// rowptr scan; also emits partition staging offsets pstart[p]=rowptr[512p]-512p.
__global__ __launch_bounds__(1024) void k_scan(const int* __restrict__ counts,
                                               int* __restrict__ rowptr,
                                               int* __restrict__ pstart, int n) {
    const int T = 1024;
    int t = threadIdx.x;
    int per = (n + T - 1) / T;
    int beg = t * per;
    int end = beg + per; if (end > n) end = n; if (beg > n) beg = n;
    int sum = 0;
    for (int i = beg; i < end; ++i) sum += counts[i] + 1;   // +1 self loop
    __shared__ int sbuf[T];
    sbuf[t] = sum;
    __syncthreads();
    for (int off = 1; off < T; off <<= 1) {
        int v = (t >= off) ? sbuf[t - off] : 0;
        __syncthreads();
        sbuf[t] += v;
        __syncthreads();
    }
    int run = sbuf[t] - sum;     // exclusive prefix
    for (int i = beg; i < end; ++i) {
        rowptr[i] = run;
        if ((i & (PSIZE - 1)) == 0) pstart[i >> PSHIFT] = run - i;
        run += counts[i] + 1;
    }
    if (t == T - 1) {
        rowptr[n] = run;
        pstart[(n + PSIZE - 1) >> PSHIFT] = run - n;   // == E
    }
}

// Pass A: block-local binning. LDS histogram -> local ranks; one global atomic
// per (block, partition) reserves a contiguous span; bursts written by one CU.
__global__ __launch_bounds__(256) void k_part(const int* __restrict__ ei,
                                              const int* __restrict__ pstart,
                                              int* __restrict__ pfill,
                                              unsigned long long* __restrict__ staged,
                                              int E, int NP) {
    __shared__ int hist[MAXP];
    __shared__ int base[MAXP];
    const int tid = threadIdx.x;
    const int j0 = blockIdx.x * CHUNK;
    for (int i = tid; i < NP; i += 256) hist[i] = 0;
    __syncthreads();
    int part[EPT], rank[EPT];
    unsigned long long rec[EPT];
#pragma unroll
    for (int e = 0; e < EPT; ++e) {
        int j = j0 + e * 256 + tid;
        part[e] = -1;
        if (j < E) {
            int s = ei[j], d = ei[E + j];
            part[e] = d >> PSHIFT;
            rec[e] = ((unsigned long long)(unsigned)d << 32) | (unsigned)s;
            rank[e] = atomicAdd(&hist[part[e]], 1);
        }
    }
    __syncthreads();
    for (int i = tid; i < NP; i += 256)
        base[i] = hist[i] ? atomicAdd(&pfill[i], hist[i]) : 0;
    __syncthreads();
#pragma unroll
    for (int e = 0; e < EPT; ++e)
        if (part[e] >= 0)
            staged[pstart[part[e]] + base[part[e]] + rank[e]] = rec[e];
}

// Pass B: one block per partition; fill counters in LDS; csr window (~67KB)
// written by a single CU -> write amp ~1.
__global__ __launch_bounds__(1024) void k_scatter3(
    const unsigned long long* __restrict__ staged, const int* __restrict__ rowptr,
    const int* __restrict__ pstart, int* __restrict__ csr, int n) {
    const int p = blockIdx.x;
    const int d0 = p << PSHIFT;
    const int d1 = min(n, d0 + PSIZE);
    __shared__ int lfill[PSIZE];
    const int tid = threadIdx.x;
    for (int i = tid; i < PSIZE; i += 1024) lfill[i] = 0;
    for (int i = d0 + tid; i < d1; i += 1024) csr[rowptr[i]] = i;   // self loops
    __syncthreads();
    const int rbeg = pstart[p], rend = pstart[p + 1];
    for (int r = rbeg + tid; r < rend; r += 1024) {
        unsigned long long v = staged[r];
        int d = (int)(v >> 32), s = (int)(v & 0xffffffffu);
        int pos = rowptr[d] + 1 + atomicAdd(&lfill[d - d0], 1);
        csr[pos] = s;
    }
}

// ---- GEMM v3: MFMA bf16. h = x@W, fused attention dots ---------------------
// W packed once into LDS in B-fragment order WB[kb][tile][lane][8] (bf16),
// so the inner-loop B read is one contiguous ds_read_b128 per lane.
// Per wave: 16-row stripe x 128 cols, 4 k-steps x 8 mfma_f32_16x16x32_bf16.
// C/D layout: col = lane&15, row = (lane>>4)*4 + q (guide-verified).

__global__ __launch_bounds__(256) void k_gemm3(
    const float* __restrict__ x, const float* __restrict__ W,
    const float* __restrict__ a_s, const float* __restrict__ a_d,
    __hip_bfloat16* __restrict__ hb, float* __restrict__ as_o,
    float* __restrict__ ad_o, int n) {
    __shared__ short WB[4 * 8 * 64 * 8];   // 16384 bf16 = 32 KB
    const int tid = threadIdx.x;
    for (int i = tid; i < CH * CH; i += 256) {
        int k = i >> 7, c = i & 127;
        int kb = k >> 5, kk = k & 31;
        int t = c >> 4;
        int ln = (c & 15) | ((kk >> 3) << 4);
        int j = kk & 7;
        WB[(((kb << 3) + t) << 9) + (ln << 3) + j] = bfc(W[i]);
    }
    __syncthreads();
    const int lane = tid & 63;
    const int wid = tid >> 6;
    const int l15 = lane & 15;
    const int lhi = lane >> 4;
    float asl[8], adl[8];
#pragma unroll
    for (int t = 0; t < 8; ++t) {
        asl[t] = a_s[t * 16 + l15];
        adl[t] = a_d[t * 16 + l15];
    }
#pragma unroll
    for (int s = 0; s < 2; ++s) {
        int r0 = blockIdx.x * 128 + s * 64 + wid * 16;
        if (r0 >= n) break;
        int ar = r0 + l15; if (ar >= n) ar = n - 1;
        const float* xr = x + (size_t)ar * CH + lhi * 8;
        f32x4 acc[8];
#pragma unroll
        for (int t = 0; t < 8; ++t) acc[t] = (f32x4){0.f, 0.f, 0.f, 0.f};
#pragma unroll
        for (int kb = 0; kb < 4; ++kb) {
            float4 xa = *(const float4*)(xr + kb * 32);
            float4 xb = *(const float4*)(xr + kb * 32 + 4);
            short8 af;
            af[0] = bfc(xa.x); af[1] = bfc(xa.y); af[2] = bfc(xa.z); af[3] = bfc(xa.w);
            af[4] = bfc(xb.x); af[5] = bfc(xb.y); af[6] = bfc(xb.z); af[7] = bfc(xb.w);
#pragma unroll
            for (int t = 0; t < 8; ++t) {
                short8 bv = ((const short8*)WB)[(((kb << 3) + t) << 6) | lane];
                acc[t] = __builtin_amdgcn_mfma_f32_16x16x32_bf16(af, bv, acc[t], 0, 0, 0);
            }
        }
        // epilogue: h store (bf16) + attention dots from fp32 accumulators
        float pa[4] = {0.f, 0.f, 0.f, 0.f}, pd[4] = {0.f, 0.f, 0.f, 0.f};
#pragma unroll
        for (int t = 0; t < 8; ++t) {
#pragma unroll
            for (int q = 0; q < 4; ++q) {
                int row = r0 + lhi * 4 + q;
                if (row < n)
                    hb[(size_t)row * CH + t * 16 + l15] = __float2bfloat16(acc[t][q]);
                pa[q] += acc[t][q] * asl[t];
                pd[q] += acc[t][q] * adl[t];
            }
        }
#pragma unroll
        for (int q = 0; q < 4; ++q) {
#pragma unroll
            for (int o = 1; o < 16; o <<= 1) {
                pa[q] += __shfl_xor(pa[q], o);
                pd[q] += __shfl_xor(pd[q], o);
            }
        }
        if (l15 == 0) {
#pragma unroll
            for (int q = 0; q < 4; ++q) {
                int row = r0 + lhi * 4 + q;
                if (row < n) { as_o[row] = pa[q]; ad_o[row] = pd[q]; }
            }
        }
    }
}

// ---- fused softmax + aggregation: one wave per node ------------------------

__global__ __launch_bounds__(256) void k_fused_agg(
    const int* __restrict__ rowptr, const int* __restrict__ csr,
    const float* __restrict__ as_v, const float* __restrict__ ad_v,
    float* __restrict__ wedge, const __hip_bfloat16* __restrict__ hb,
    const float* __restrict__ bias, float* __restrict__ out, int n) {
    int gw = (int)((blockIdx.x * (size_t)blockDim.x + threadIdx.x) >> 6);
    int lane = threadIdx.x & 63;
    if (gw >= n) return;
    int beg = rowptr[gw], end = rowptr[gw + 1];
    float adi = ad_v[gw];

    // Phase A: scores + max (coalesced wedge writes)
    float m = -1e30f;
    for (int p = beg + lane; p < end; p += 64) {
        float e = lrelu(as_v[csr[p]] + adi);
        wedge[p] = e;
        m = fmaxf(m, e);
    }
#pragma unroll
    for (int o = 32; o > 0; o >>= 1) m = fmaxf(m, __shfl_xor(m, o));

    // Phase B: exp + denom
    float s = 0.f;
    for (int p = beg + lane; p < end; p += 64) {
        float wv = __expf(wedge[p] - m);
        wedge[p] = wv;
        s += wv;
    }
#pragma unroll
    for (int o = 32; o > 0; o >>= 1) s += __shfl_xor(s, o);
    float inv = 1.0f / s;

    // Phase C: bf16 gather-accumulate, 4 edges per iteration
    const int quarter = lane >> 4;     // edge sub-slot 0..3
    const int c8 = lane & 15;          // 8-channel block
    float acc[8];
#pragma unroll
    for (int k = 0; k < 8; ++k) acc[k] = 0.f;
    for (int p = beg; p < end; p += 4) {
        int pp = p + quarter;
        float wv; int src;
        if (pp < end) { wv = wedge[pp]; src = csr[pp]; }
        else { wv = 0.f; src = 0; }
        uint4 hv = ((const uint4*)hb)[(size_t)src * 16 + c8];
        acc[0] += wv * __uint_as_float(hv.x << 16);
        acc[1] += wv * __uint_as_float(hv.x & 0xffff0000u);
        acc[2] += wv * __uint_as_float(hv.y << 16);
        acc[3] += wv * __uint_as_float(hv.y & 0xffff0000u);
        acc[4] += wv * __uint_as_float(hv.z << 16);
        acc[5] += wv * __uint_as_float(hv.z & 0xffff0000u);
        acc[6] += wv * __uint_as_float(hv.w << 16);
        acc[7] += wv * __uint_as_float(hv.w & 0xffff0000u);
    }
#pragma unroll
    for (int k = 0; k < 8; ++k) {
        acc[k] += __shfl_xor(acc[k], 16);
        acc[k] += __shfl_xor(acc[k], 32);
    }
    if (quarter == 0) {
        const float4 bv0 = ((const float4*)bias)[c8 * 2];
        const float4 bv1 = ((const float4*)bias)[c8 * 2 + 1];
        float4 o0, o1;
        o0.x = seluf(acc[0] * inv + bv0.x);
        o0.y = seluf(acc[1] * inv + bv0.y);
        o0.z = seluf(acc[2] * inv + bv0.z);
        o0.w = seluf(acc[3] * inv + bv0.w);
        o1.x = seluf(acc[4] * inv + bv1.x);
        o1.y = seluf(acc[5] * inv + bv1.y);
        o1.z = seluf(acc[6] * inv + bv1.z);
        o1.w = seluf(acc[7] * inv + bv1.w);
        ((float4*)out)[(size_t)gw * 32 + c8 * 2] = o0;
        ((float4*)out)[(size_t)gw * 32 + c8 * 2 + 1] = o1;
    }
}

// ---- global mean pool (batch is sorted) ------------------------------------

__device__ int lower_bound_dev(const int* a, int n, int key) {
    int lo = 0, hi = n;
    while (lo < hi) {
        int mid = (lo + hi) >> 1;
        if (a[mid] < key) lo = mid + 1; else hi = mid;
    }
    return lo;
}

__global__ __launch_bounds__(256) void k_pool(const float* __restrict__ x,
                                              const int* __restrict__ batchv,
                                              float* __restrict__ outp, int n) {
    int g = blockIdx.x;
    int lo = lower_bound_dev(batchv, n, g);
    int hi = lower_bound_dev(batchv, n, g + 1);
    int lane = threadIdx.x & 63, wv = threadIdx.x >> 6;
    float sx = 0.f, sy = 0.f;
    for (int i = lo + wv; i < hi; i += 4) {
        float2 v = ((const float2*)x)[(size_t)i * 64 + lane];
        sx += v.x;
        sy += v.y;
    }
    __shared__ float2 red[4][64];
    red[wv][lane] = make_float2(sx, sy);
    __syncthreads();
    if (wv == 0) {
        float2 a = red[0][lane], b = red[1][lane], c = red[2][lane], d = red[3][lane];
        int cntv = hi - lo; if (cntv < 1) cntv = 1;
        float inv = 1.0f / (float)cntv;
        outp[(size_t)g * CH + 2 * lane] = (a.x + b.x + c.x + d.x) * inv;
        outp[(size_t)g * CH + 2 * lane + 1] = (a.y + b.y + c.y + d.y) * inv;
    }
}

// ---- orchestration ---------------------------------------------------------

extern "C" void kernel_launch(void* const* d_in, const int* in_sizes, int n_in,
                              void* d_out, int out_size, void* d_ws, size_t ws_size,
                              hipStream_t stream) {
    const float* u   = (const float*)d_in[0];
    const float* W1  = (const float*)d_in[1];
    const float* as1 = (const float*)d_in[2];
    const float* ad1 = (const float*)d_in[3];
    const float* b1  = (const float*)d_in[4];
    const float* W2  = (const float*)d_in[5];
    const float* as2 = (const float*)d_in[6];
    const float* ad2 = (const float*)d_in[7];
    const float* b2  = (const float*)d_in[8];
    const int* ei    = (const int*)d_in[9];
    const int* batchv= (const int*)d_in[10];

    const int N = in_sizes[0] / CH;
    const int E = in_sizes[9] / 2;
    const int M = E + N;
    const int NP = (N + PSIZE - 1) >> PSHIFT;

    char* p = (char*)d_ws;
    auto alloc = [&](size_t bytes) {
        char* r = p;
        p += (bytes + 255) & ~(size_t)255;
        return r;
    };
    int*   counts = (int*)alloc((size_t)N * 4);
    int*   pfill  = (int*)alloc((size_t)NP * 4);
    size_t zbytes = (size_t)(p - (char*)d_ws);      // zero counts+pfill
    int*   rowptr = (int*)alloc((size_t)(N + 1) * 4);
    int*   pstart = (int*)alloc((size_t)(NP + 1) * 4);
    int*   csr    = (int*)alloc((size_t)M * 4);
    float* wedge  = (float*)alloc((size_t)M * 4);
    float* asv    = (float*)alloc((size_t)N * 4);
    float* adv    = (float*)alloc((size_t)N * 4);
    // staged aliases hbuf: staged is fully consumed by k_scatter3 before the
    // first k_gemm3 writes hbuf.
    size_t hbytes = (size_t)N * CH * 2;
    size_t sbytes = (size_t)E * 8;
    char*  hs     = alloc(hbytes > sbytes ? hbytes : sbytes);
    __hip_bfloat16* hbuf = (__hip_bfloat16*)hs;
    unsigned long long* staged = (unsigned long long*)hs;
    float* x2     = (float*)alloc((size_t)N * CH * 4);

    hipMemsetAsync(d_ws, 0, zbytes, stream);

    k_hist<<<2048, 256, 0, stream>>>(ei, counts, E);
    k_scan<<<1, 1024, 0, stream>>>(counts, rowptr, pstart, N);
    k_part<<<(E + CHUNK - 1) / CHUNK, 256, 0, stream>>>(ei, pstart, pfill, staged, E, NP);
    k_scatter3<<<NP, 1024, 0, stream>>>(staged, rowptr, pstart, csr, N);

    const int gblocks = (N + 127) / 128;

    // layer 1
    k_gemm3<<<gblocks, 256, 0, stream>>>(u, W1, as1, ad1, hbuf, asv, adv, N);
    k_fused_agg<<<(N * 64 + 255) / 256, 256, 0, stream>>>(rowptr, csr, asv, adv, wedge, hbuf, b1, x2, N);

    // layer 2
    k_gemm3<<<gblocks, 256, 0, stream>>>(x2, W2, as2, ad2, hbuf, asv, adv, N);
    k_fused_agg<<<(N * 64 + 255) / 256, 256, 0, stream>>>(rowptr, csr, asv, adv, wedge, hbuf, b2, x2, N);

    k_pool<<<64, 256, 0, stream>>>(x2, batchv, (float*)d_out, N);
}

// Round 8
// 340.498 us; speedup vs baseline: 2.3668x; 1.2947x over previous
//
#include <hip/hip_runtime.h>
#include <hip/hip_bf16.h>
#include <math.h>

#define CH 128
#define PSHIFT 9              // 512 nodes per partition
#define PSIZE (1 << PSHIFT)
#define CHUNK 2048            // edges per block in k_part
#define EPT 8                 // edges per thread (256 * 8 = 2048)
#define MAXP 128              // max partitions (N <= 65536)

typedef __attribute__((ext_vector_type(8))) short short8;
typedef __attribute__((ext_vector_type(4))) float f32x4;

__device__ __forceinline__ float seluf(float x) {
    const float scale = 1.0507009873554804934193349852946f;
    const float alpha = 1.6732632423543772848170429916717f;
    return x > 0.0f ? scale * x : scale * alpha * (__expf(x) - 1.0f);
}

__device__ __forceinline__ float lrelu(float x) {
    return x > 0.0f ? x : 0.2f * x;
}

__device__ __forceinline__ short bfc(float f) {
    union { __hip_bfloat16 b; short s; } u;
    u.b = __float2bfloat16(f);
    return u.s;
}

// ---- CSR build (partition-local, no global per-node histogram/scan) --------

// Per-partition edge histogram via block LDS + one global add per partition.
__global__ __launch_bounds__(256) void k_phist(const int* __restrict__ ei,
                                               int* __restrict__ pcount,
                                               int E, int NP) {
    __shared__ int hist[MAXP];
    for (int i = threadIdx.x; i < NP; i += 256) hist[i] = 0;
    __syncthreads();
    int stride = gridDim.x * blockDim.x;
    for (int j = blockIdx.x * blockDim.x + threadIdx.x; j < E; j += stride)
        atomicAdd(&hist[ei[E + j] >> PSHIFT], 1);
    __syncthreads();
    for (int i = threadIdx.x; i < NP; i += 256)
        if (hist[i]) atomicAdd(&pcount[i], hist[i]);
}

// Tiny top-level scan over NP partitions -> pe[] (staged bases), rowptr[n].
__global__ __launch_bounds__(128) void k_ptop(const int* __restrict__ pcount,
                                              int* __restrict__ pe,
                                              int* __restrict__ rowptr,
                                              int n, int E, int NP) {
    __shared__ int sb[128];
    int t = threadIdx.x;
    int v = (t < NP) ? pcount[t] : 0;
    sb[t] = v;
    __syncthreads();
    for (int off = 1; off < 128; off <<= 1) {
        int u = (t >= off) ? sb[t - off] : 0;
        __syncthreads();
        sb[t] += u;
        __syncthreads();
    }
    if (t < NP) pe[t] = sb[t] - v;          // exclusive prefix
    if (t == NP - 1) {
        pe[NP] = sb[t];                      // == E
        rowptr[n] = E + n;
    }
}

// Pass A: block-local binning. LDS histogram -> local ranks; one global atomic
// per (block, partition) reserves a contiguous span; bursts written by one CU.
__global__ __launch_bounds__(256) void k_part(const int* __restrict__ ei,
                                              const int* __restrict__ pe,
                                              int* __restrict__ pfill,
                                              unsigned long long* __restrict__ staged,
                                              int E, int NP) {
    __shared__ int hist[MAXP];
    __shared__ int base[MAXP];
    const int tid = threadIdx.x;
    const int j0 = blockIdx.x * CHUNK;
    for (int i = tid; i < NP; i += 256) hist[i] = 0;
    __syncthreads();
    int part[EPT], rank[EPT];
    unsigned long long rec[EPT];
#pragma unroll
    for (int e = 0; e < EPT; ++e) {
        int j = j0 + e * 256 + tid;
        part[e] = -1;
        if (j < E) {
            int s = ei[j], d = ei[E + j];
            part[e] = d >> PSHIFT;
            rec[e] = ((unsigned long long)(unsigned)d << 32) | (unsigned)s;
            rank[e] = atomicAdd(&hist[part[e]], 1);
        }
    }
    __syncthreads();
    for (int i = tid; i < NP; i += 256)
        base[i] = hist[i] ? atomicAdd(&pfill[i], hist[i]) : 0;
    __syncthreads();
#pragma unroll
    for (int e = 0; e < EPT; ++e)
        if (part[e] >= 0)
            staged[pe[part[e]] + base[part[e]] + rank[e]] = rec[e];
}

// Pass B: one block per partition. Per-node histogram + scan + scatter all in
// LDS; rowptr and csr windows written by a single CU.
__global__ __launch_bounds__(1024) void k_build(
    const unsigned long long* __restrict__ staged, const int* __restrict__ pe,
    int* __restrict__ rowptr, int* __restrict__ csr, int n) {
    const int p = blockIdx.x;
    const int d0 = p << PSHIFT;
    __shared__ int lcnt[PSIZE];
    __shared__ int lrow[PSIZE];
    __shared__ int sc[PSIZE];
    const int tid = threadIdx.x;
    if (tid < PSIZE) lcnt[tid] = 0;
    __syncthreads();
    const int rbeg = pe[p], rend = pe[p + 1];
    const int rb = rbeg + d0;            // rowptr base (self-loop slots before)
    for (int r = rbeg + tid; r < rend; r += 1024)
        atomicAdd(&lcnt[(int)(staged[r] >> 32) - d0], 1);
    __syncthreads();
    int myv = 0;
    if (tid < PSIZE) {
        myv = (d0 + tid < n) ? lcnt[tid] + 1 : 0;
        sc[tid] = myv;
    }
    __syncthreads();
    for (int off = 1; off < PSIZE; off <<= 1) {
        int u = 0;
        if (tid < PSIZE && tid >= off) u = sc[tid - off];
        __syncthreads();
        if (tid < PSIZE) sc[tid] += u;
        __syncthreads();
    }
    if (tid < PSIZE && d0 + tid < n) {
        int rp = rb + sc[tid] - myv;     // exclusive prefix
        lrow[tid] = rp;
        rowptr[d0 + tid] = rp;
        csr[rp] = d0 + tid;              // self loop
        lcnt[tid] = 0;                   // reuse as fill counter
    }
    __syncthreads();
    for (int r = rbeg + tid; r < rend; r += 1024) {
        unsigned long long v = staged[r];
        int d = (int)(v >> 32), s = (int)(v & 0xffffffffu);
        int pos = lrow[d - d0] + 1 + atomicAdd(&lcnt[d - d0], 1);
        csr[pos] = s;
    }
}

// ---- GEMM v3: MFMA bf16. h = x@W, fused attention dots ---------------------
// W packed once into LDS in B-fragment order WB[kb][tile][lane][8] (bf16),
// so the inner-loop B read is one contiguous ds_read_b128 per lane.
// Per wave: 16-row stripe x 128 cols, 4 k-steps x 8 mfma_f32_16x16x32_bf16.
// C/D layout: col = lane&15, row = (lane>>4)*4 + q (guide-verified).

__global__ __launch_bounds__(256) void k_gemm3(
    const float* __restrict__ x, const float* __restrict__ W,
    const float* __restrict__ a_s, const float* __restrict__ a_d,
    __hip_bfloat16* __restrict__ hb, float* __restrict__ as_o,
    float* __restrict__ ad_o, int n) {
    __shared__ short WB[4 * 8 * 64 * 8];   // 16384 bf16 = 32 KB
    const int tid = threadIdx.x;
    for (int i = tid; i < CH * CH; i += 256) {
        int k = i >> 7, c = i & 127;
        int kb = k >> 5, kk = k & 31;
        int t = c >> 4;
        int ln = (c & 15) | ((kk >> 3) << 4);
        int j = kk & 7;
        WB[(((kb << 3) + t) << 9) + (ln << 3) + j] = bfc(W[i]);
    }
    __syncthreads();
    const int lane = tid & 63;
    const int wid = tid >> 6;
    const int l15 = lane & 15;
    const int lhi = lane >> 4;
    float asl[8], adl[8];
#pragma unroll
    for (int t = 0; t < 8; ++t) {
        asl[t] = a_s[t * 16 + l15];
        adl[t] = a_d[t * 16 + l15];
    }
#pragma unroll
    for (int s = 0; s < 2; ++s) {
        int r0 = blockIdx.x * 128 + s * 64 + wid * 16;
        if (r0 >= n) break;
        int ar = r0 + l15; if (ar >= n) ar = n - 1;
        const float* xr = x + (size_t)ar * CH + lhi * 8;
        f32x4 acc[8];
#pragma unroll
        for (int t = 0; t < 8; ++t) acc[t] = (f32x4){0.f, 0.f, 0.f, 0.f};
#pragma unroll
        for (int kb = 0; kb < 4; ++kb) {
            float4 xa = *(const float4*)(xr + kb * 32);
            float4 xb = *(const float4*)(xr + kb * 32 + 4);
            short8 af;
            af[0] = bfc(xa.x); af[1] = bfc(xa.y); af[2] = bfc(xa.z); af[3] = bfc(xa.w);
            af[4] = bfc(xb.x); af[5] = bfc(xb.y); af[6] = bfc(xb.z); af[7] = bfc(xb.w);
#pragma unroll
            for (int t = 0; t < 8; ++t) {
                short8 bv = ((const short8*)WB)[(((kb << 3) + t) << 6) | lane];
                acc[t] = __builtin_amdgcn_mfma_f32_16x16x32_bf16(af, bv, acc[t], 0, 0, 0);
            }
        }
        // epilogue: h store (bf16) + attention dots from fp32 accumulators
        float pa[4] = {0.f, 0.f, 0.f, 0.f}, pd[4] = {0.f, 0.f, 0.f, 0.f};
#pragma unroll
        for (int t = 0; t < 8; ++t) {
#pragma unroll
            for (int q = 0; q < 4; ++q) {
                int row = r0 + lhi * 4 + q;
                if (row < n)
                    hb[(size_t)row * CH + t * 16 + l15] = __float2bfloat16(acc[t][q]);
                pa[q] += acc[t][q] * asl[t];
                pd[q] += acc[t][q] * adl[t];
            }
        }
#pragma unroll
        for (int q = 0; q < 4; ++q) {
#pragma unroll
            for (int o = 1; o < 16; o <<= 1) {
                pa[q] += __shfl_xor(pa[q], o);
                pd[q] += __shfl_xor(pd[q], o);
            }
        }
        if (l15 == 0) {
#pragma unroll
            for (int q = 0; q < 4; ++q) {
                int row = r0 + lhi * 4 + q;
                if (row < n) { as_o[row] = pa[q]; ad_o[row] = pd[q]; }
            }
        }
    }
}

// ---- fused softmax + aggregation: one wave per node ------------------------

__global__ __launch_bounds__(256) void k_fused_agg(
    const int* __restrict__ rowptr, const int* __restrict__ csr,
    const float* __restrict__ as_v, const float* __restrict__ ad_v,
    float* __restrict__ wedge, const __hip_bfloat16* __restrict__ hb,
    const float* __restrict__ bias, float* __restrict__ out, int n) {
    int gw = (int)((blockIdx.x * (size_t)blockDim.x + threadIdx.x) >> 6);
    int lane = threadIdx.x & 63;
    if (gw >= n) return;
    int beg = rowptr[gw], end = rowptr[gw + 1];
    float adi = ad_v[gw];

    // Phase A: scores + max (coalesced wedge writes)
    float m = -1e30f;
    for (int p = beg + lane; p < end; p += 64) {
        float e = lrelu(as_v[csr[p]] + adi);
        wedge[p] = e;
        m = fmaxf(m, e);
    }
#pragma unroll
    for (int o = 32; o > 0; o >>= 1) m = fmaxf(m, __shfl_xor(m, o));

    // Phase B: exp + denom
    float s = 0.f;
    for (int p = beg + lane; p < end; p += 64) {
        float wv = __expf(wedge[p] - m);
        wedge[p] = wv;
        s += wv;
    }
#pragma unroll
    for (int o = 32; o > 0; o >>= 1) s += __shfl_xor(s, o);
    float inv = 1.0f / s;

    // Phase C: bf16 gather-accumulate, 4 edges per iteration
    const int quarter = lane >> 4;     // edge sub-slot 0..3
    const int c8 = lane & 15;          // 8-channel block
    float acc[8];
#pragma unroll
    for (int k = 0; k < 8; ++k) acc[k] = 0.f;
    for (int p = beg; p < end; p += 4) {
        int pp = p + quarter;
        float wv; int src;
        if (pp < end) { wv = wedge[pp]; src = csr[pp]; }
        else { wv = 0.f; src = 0; }
        uint4 hv = ((const uint4*)hb)[(size_t)src * 16 + c8];
        acc[0] += wv * __uint_as_float(hv.x << 16);
        acc[1] += wv * __uint_as_float(hv.x & 0xffff0000u);
        acc[2] += wv * __uint_as_float(hv.y << 16);
        acc[3] += wv * __uint_as_float(hv.y & 0xffff0000u);
        acc[4] += wv * __uint_as_float(hv.z << 16);
        acc[5] += wv * __uint_as_float(hv.z & 0xffff0000u);
        acc[6] += wv * __uint_as_float(hv.w << 16);
        acc[7] += wv * __uint_as_float(hv.w & 0xffff0000u);
    }
#pragma unroll
    for (int k = 0; k < 8; ++k) {
        acc[k] += __shfl_xor(acc[k], 16);
        acc[k] += __shfl_xor(acc[k], 32);
    }
    if (quarter == 0) {
        const float4 bv0 = ((const float4*)bias)[c8 * 2];
        const float4 bv1 = ((const float4*)bias)[c8 * 2 + 1];
        float4 o0, o1;
        o0.x = seluf(acc[0] * inv + bv0.x);
        o0.y = seluf(acc[1] * inv + bv0.y);
        o0.z = seluf(acc[2] * inv + bv0.z);
        o0.w = seluf(acc[3] * inv + bv0.w);
        o1.x = seluf(acc[4] * inv + bv1.x);
        o1.y = seluf(acc[5] * inv + bv1.y);
        o1.z = seluf(acc[6] * inv + bv1.z);
        o1.w = seluf(acc[7] * inv + bv1.w);
        ((float4*)out)[(size_t)gw * 32 + c8 * 2] = o0;
        ((float4*)out)[(size_t)gw * 32 + c8 * 2 + 1] = o1;
    }
}

// ---- global mean pool (batch is sorted) ------------------------------------

__device__ int lower_bound_dev(const int* a, int n, int key) {
    int lo = 0, hi = n;
    while (lo < hi) {
        int mid = (lo + hi) >> 1;
        if (a[mid] < key) lo = mid + 1; else hi = mid;
    }
    return lo;
}

__global__ __launch_bounds__(256) void k_pool(const float* __restrict__ x,
                                              const int* __restrict__ batchv,
                                              float* __restrict__ outp, int n) {
    int g = blockIdx.x;
    int lo = lower_bound_dev(batchv, n, g);
    int hi = lower_bound_dev(batchv, n, g + 1);
    int lane = threadIdx.x & 63, wv = threadIdx.x >> 6;
    float sx = 0.f, sy = 0.f;
    for (int i = lo + wv; i < hi; i += 4) {
        float2 v = ((const float2*)x)[(size_t)i * 64 + lane];
        sx += v.x;
        sy += v.y;
    }
    __shared__ float2 red[4][64];
    red[wv][lane] = make_float2(sx, sy);
    __syncthreads();
    if (wv == 0) {
        float2 a = red[0][lane], b = red[1][lane], c = red[2][lane], d = red[3][lane];
        int cntv = hi - lo; if (cntv < 1) cntv = 1;
        float inv = 1.0f / (float)cntv;
        outp[(size_t)g * CH + 2 * lane] = (a.x + b.x + c.x + d.x) * inv;
        outp[(size_t)g * CH + 2 * lane + 1] = (a.y + b.y + c.y + d.y) * inv;
    }
}

// ---- orchestration ---------------------------------------------------------

extern "C" void kernel_launch(void* const* d_in, const int* in_sizes, int n_in,
                              void* d_out, int out_size, void* d_ws, size_t ws_size,
                              hipStream_t stream) {
    const float* u   = (const float*)d_in[0];
    const float* W1  = (const float*)d_in[1];
    const float* as1 = (const float*)d_in[2];
    const float* ad1 = (const float*)d_in[3];
    const float* b1  = (const float*)d_in[4];
    const float* W2  = (const float*)d_in[5];
    const float* as2 = (const float*)d_in[6];
    const float* ad2 = (const float*)d_in[7];
    const float* b2  = (const float*)d_in[8];
    const int* ei    = (const int*)d_in[9];
    const int* batchv= (const int*)d_in[10];

    const int N = in_sizes[0] / CH;
    const int E = in_sizes[9] / 2;
    const int M = E + N;
    const int NP = (N + PSIZE - 1) >> PSHIFT;

    char* p = (char*)d_ws;
    auto alloc = [&](size_t bytes) {
        char* r = p;
        p += (bytes + 255) & ~(size_t)255;
        return r;
    };
    int*   pcount = (int*)alloc((size_t)NP * 4);
    int*   pfill  = (int*)alloc((size_t)NP * 4);
    size_t zbytes = (size_t)(p - (char*)d_ws);      // zero pcount+pfill
    int*   rowptr = (int*)alloc((size_t)(N + 1) * 4);
    int*   pe     = (int*)alloc((size_t)(NP + 1) * 4);
    int*   csr    = (int*)alloc((size_t)M * 4);
    float* wedge  = (float*)alloc((size_t)M * 4);
    float* asv    = (float*)alloc((size_t)N * 4);
    float* adv    = (float*)alloc((size_t)N * 4);
    // staged aliases hbuf: staged is fully consumed by k_build before the
    // first k_gemm3 writes hbuf.
    size_t hbytes = (size_t)N * CH * 2;
    size_t sbytes = (size_t)E * 8;
    char*  hs     = alloc(hbytes > sbytes ? hbytes : sbytes);
    __hip_bfloat16* hbuf = (__hip_bfloat16*)hs;
    unsigned long long* staged = (unsigned long long*)hs;
    float* x2     = (float*)alloc((size_t)N * CH * 4);

    hipMemsetAsync(d_ws, 0, zbytes, stream);

    k_phist<<<2048, 256, 0, stream>>>(ei, pcount, E, NP);
    k_ptop<<<1, 128, 0, stream>>>(pcount, pe, rowptr, N, E, NP);
    k_part<<<(E + CHUNK - 1) / CHUNK, 256, 0, stream>>>(ei, pe, pfill, staged, E, NP);
    k_build<<<NP, 1024, 0, stream>>>(staged, pe, rowptr, csr, N);

    const int gblocks = (N + 127) / 128;

    // layer 1
    k_gemm3<<<gblocks, 256, 0, stream>>>(u, W1, as1, ad1, hbuf, asv, adv, N);
    k_fused_agg<<<(N * 64 + 255) / 256, 256, 0, stream>>>(rowptr, csr, asv, adv, wedge, hbuf, b1, x2, N);

    // layer 2
    k_gemm3<<<gblocks, 256, 0, stream>>>(x2, W2, as2, ad2, hbuf, asv, adv, N);
    k_fused_agg<<<(N * 64 + 255) / 256, 256, 0, stream>>>(rowptr, csr, asv, adv, wedge, hbuf, b2, x2, N);

    k_pool<<<64, 256, 0, stream>>>(x2, batchv, (float*)d_out, N);
}

// Round 9
// 267.748 us; speedup vs baseline: 3.0099x; 1.2717x over previous
//
#include <hip/hip_runtime.h>
#include <hip/hip_bf16.h>
#include <math.h>

#define CH 128
#define PSHIFT 9              // 512 nodes per partition
#define PSIZE (1 << PSHIFT)
#define CHUNK 2048            // edges per block in k_part
#define EPT 8                 // edges per thread (256 * 8 = 2048)
#define MAXP 128              // max partitions (N <= 65536)
#define PCAP 24576            // staging capacity per partition (mean 16384 + 64 sigma)

typedef __attribute__((ext_vector_type(8))) short short8;
typedef __attribute__((ext_vector_type(4))) float f32x4;

__device__ __forceinline__ float seluf(float x) {
    const float scale = 1.0507009873554804934193349852946f;
    const float alpha = 1.6732632423543772848170429916717f;
    return x > 0.0f ? scale * x : scale * alpha * (__expf(x) - 1.0f);
}

__device__ __forceinline__ float lrelu(float x) {
    return x > 0.0f ? x : 0.2f * x;
}

__device__ __forceinline__ short bfc(float f) {
    union { __hip_bfloat16 b; short s; } u;
    u.b = __float2bfloat16(f);
    return u.s;
}

__device__ __forceinline__ unsigned pk(float lo, float hi) {
    return ((unsigned)(unsigned short)bfc(hi) << 16) | (unsigned short)bfc(lo);
}

// ---- CSR build -------------------------------------------------------------
// k_part: block-local binning into fixed-capacity partition slots; pfill
// doubles as the per-partition histogram (k_phist eliminated).

__global__ __launch_bounds__(256) void k_part(const int* __restrict__ ei,
                                              int* __restrict__ pfill,
                                              unsigned long long* __restrict__ staged,
                                              int E, int NP) {
    __shared__ int hist[MAXP];
    __shared__ int base[MAXP];
    const int tid = threadIdx.x;
    const int j0 = blockIdx.x * CHUNK;
    for (int i = tid; i < NP; i += 256) hist[i] = 0;
    __syncthreads();
    int part[EPT], rank[EPT];
    unsigned long long rec[EPT];
#pragma unroll
    for (int e = 0; e < EPT; ++e) {
        int j = j0 + e * 256 + tid;
        part[e] = -1;
        if (j < E) {
            int s = ei[j], d = ei[E + j];
            part[e] = d >> PSHIFT;
            rec[e] = ((unsigned long long)(unsigned)d << 32) | (unsigned)s;
            rank[e] = atomicAdd(&hist[part[e]], 1);
        }
    }
    __syncthreads();
    for (int i = tid; i < NP; i += 256)
        base[i] = hist[i] ? atomicAdd(&pfill[i], hist[i]) : 0;
    __syncthreads();
#pragma unroll
    for (int e = 0; e < EPT; ++e)
        if (part[e] >= 0)
            staged[(size_t)part[e] * PCAP + base[part[e]] + rank[e]] = rec[e];
}

// Tiny scan over NP partition counts -> cumulative edge bases; rowptr[n].
__global__ __launch_bounds__(128) void k_ptop(const int* __restrict__ pfill,
                                              int* __restrict__ pbase,
                                              int* __restrict__ rowptr,
                                              int n, int E, int NP) {
    __shared__ int sb[128];
    int t = threadIdx.x;
    int v = (t < NP) ? pfill[t] : 0;
    sb[t] = v;
    __syncthreads();
    for (int off = 1; off < 128; off <<= 1) {
        int u = (t >= off) ? sb[t - off] : 0;
        __syncthreads();
        sb[t] += u;
        __syncthreads();
    }
    if (t < NP) pbase[t] = sb[t] - v;       // exclusive prefix of edge counts
    if (t == NP - 1) {
        pbase[NP] = sb[t];                   // == E
        rowptr[n] = E + n;
    }
}

// One block per partition: per-node histogram + scan + scatter all in LDS.
__global__ __launch_bounds__(1024) void k_build(
    const unsigned long long* __restrict__ staged, const int* __restrict__ pfill,
    const int* __restrict__ pbase, int* __restrict__ rowptr, int* __restrict__ csr,
    int n) {
    const int p = blockIdx.x;
    const int d0 = p << PSHIFT;
    __shared__ int lcnt[PSIZE];
    __shared__ int lrow[PSIZE];
    __shared__ int sc[PSIZE];
    const int tid = threadIdx.x;
    if (tid < PSIZE) lcnt[tid] = 0;
    __syncthreads();
    const size_t rbeg = (size_t)p * PCAP;
    const size_t rend = rbeg + pfill[p];
    const int rb = pbase[p] + d0;        // rowptr base for this partition
    for (size_t r = rbeg + tid; r < rend; r += 1024)
        atomicAdd(&lcnt[(int)(staged[r] >> 32) - d0], 1);
    __syncthreads();
    int myv = 0;
    if (tid < PSIZE) {
        myv = (d0 + tid < n) ? lcnt[tid] + 1 : 0;
        sc[tid] = myv;
    }
    __syncthreads();
    for (int off = 1; off < PSIZE; off <<= 1) {
        int u = 0;
        if (tid < PSIZE && tid >= off) u = sc[tid - off];
        __syncthreads();
        if (tid < PSIZE) sc[tid] += u;
        __syncthreads();
    }
    if (tid < PSIZE && d0 + tid < n) {
        int rp = rb + sc[tid] - myv;     // exclusive prefix
        lrow[tid] = rp;
        rowptr[d0 + tid] = rp;
        csr[rp] = d0 + tid;              // self loop
        lcnt[tid] = 0;                   // reuse as fill counter
    }
    __syncthreads();
    for (size_t r = rbeg + tid; r < rend; r += 1024) {
        unsigned long long v = staged[r];
        int d = (int)(v >> 32), s = (int)(v & 0xffffffffu);
        int pos = lrow[d - d0] + 1 + atomicAdd(&lcnt[d - d0], 1);
        csr[pos] = s;
    }
}

// ---- GEMM v3: MFMA bf16. h = x@W, fused attention dots ---------------------
// Templated input loader: fp32 (layer 1, converts in-register) or bf16 (x2).

template <typename T>
__global__ __launch_bounds__(256) void k_gemm3(
    const T* __restrict__ x, const float* __restrict__ W,
    const float* __restrict__ a_s, const float* __restrict__ a_d,
    __hip_bfloat16* __restrict__ hb, float* __restrict__ as_o,
    float* __restrict__ ad_o, int n) {
    __shared__ short WB[4 * 8 * 64 * 8];   // 16384 bf16 = 32 KB
    const int tid = threadIdx.x;
    for (int i = tid; i < CH * CH; i += 256) {
        int k = i >> 7, c = i & 127;
        int kb = k >> 5, kk = k & 31;
        int t = c >> 4;
        int ln = (c & 15) | ((kk >> 3) << 4);
        int j = kk & 7;
        WB[(((kb << 3) + t) << 9) + (ln << 3) + j] = bfc(W[i]);
    }
    __syncthreads();
    const int lane = tid & 63;
    const int wid = tid >> 6;
    const int l15 = lane & 15;
    const int lhi = lane >> 4;
    float asl[8], adl[8];
#pragma unroll
    for (int t = 0; t < 8; ++t) {
        asl[t] = a_s[t * 16 + l15];
        adl[t] = a_d[t * 16 + l15];
    }
#pragma unroll
    for (int s = 0; s < 2; ++s) {
        int r0 = blockIdx.x * 128 + s * 64 + wid * 16;
        if (r0 >= n) break;
        int ar = r0 + l15; if (ar >= n) ar = n - 1;
        const T* xr = x + (size_t)ar * CH + lhi * 8;
        f32x4 acc[8];
#pragma unroll
        for (int t = 0; t < 8; ++t) acc[t] = (f32x4){0.f, 0.f, 0.f, 0.f};
#pragma unroll
        for (int kb = 0; kb < 4; ++kb) {
            short8 af;
            if constexpr (sizeof(T) == 4) {
                float4 xa = *(const float4*)(xr + kb * 32);
                float4 xb = *(const float4*)(xr + kb * 32 + 4);
                af[0] = bfc(xa.x); af[1] = bfc(xa.y); af[2] = bfc(xa.z); af[3] = bfc(xa.w);
                af[4] = bfc(xb.x); af[5] = bfc(xb.y); af[6] = bfc(xb.z); af[7] = bfc(xb.w);
            } else {
                af = *(const short8*)(xr + kb * 32);
            }
#pragma unroll
            for (int t = 0; t < 8; ++t) {
                short8 bv = ((const short8*)WB)[(((kb << 3) + t) << 6) | lane];
                acc[t] = __builtin_amdgcn_mfma_f32_16x16x32_bf16(af, bv, acc[t], 0, 0, 0);
            }
        }
        // epilogue: h store (bf16) + attention dots from fp32 accumulators
        float pa[4] = {0.f, 0.f, 0.f, 0.f}, pd[4] = {0.f, 0.f, 0.f, 0.f};
#pragma unroll
        for (int t = 0; t < 8; ++t) {
#pragma unroll
            for (int q = 0; q < 4; ++q) {
                int row = r0 + lhi * 4 + q;
                if (row < n)
                    hb[(size_t)row * CH + t * 16 + l15] = __float2bfloat16(acc[t][q]);
                pa[q] += acc[t][q] * asl[t];
                pd[q] += acc[t][q] * adl[t];
            }
        }
#pragma unroll
        for (int q = 0; q < 4; ++q) {
#pragma unroll
            for (int o = 1; o < 16; o <<= 1) {
                pa[q] += __shfl_xor(pa[q], o);
                pd[q] += __shfl_xor(pd[q], o);
            }
        }
        if (l15 == 0) {
#pragma unroll
            for (int q = 0; q < 4; ++q) {
                int row = r0 + lhi * 4 + q;
                if (row < n) { as_o[row] = pa[q]; ad_o[row] = pd[q]; }
            }
        }
    }
}

// ---- fused softmax + aggregation: one wave per node, bf16 out --------------
// Fast path (deg <= 64): per-edge score/src live in registers; softmax via
// shuffles; phase C pulls (w,src) with two __shfl per 4 edges. No wedge array.

__global__ __launch_bounds__(256) void k_fused_agg(
    const int* __restrict__ rowptr, const int* __restrict__ csr,
    const float* __restrict__ as_v, const float* __restrict__ ad_v,
    float* __restrict__ wedge, const __hip_bfloat16* __restrict__ hb,
    const float* __restrict__ bias, __hip_bfloat16* __restrict__ out, int n) {
    int gw = (int)((blockIdx.x * (size_t)blockDim.x + threadIdx.x) >> 6);
    int lane = threadIdx.x & 63;
    if (gw >= n) return;
    int beg = rowptr[gw], end = rowptr[gw + 1];
    int deg = end - beg;
    float adi = ad_v[gw];

    const int quarter = lane >> 4;     // edge sub-slot 0..3
    const int c8 = lane & 15;          // 8-channel block
    float acc[8];
#pragma unroll
    for (int k = 0; k < 8; ++k) acc[k] = 0.f;
    float inv;

    if (deg <= 64) {
        // ---- register-resident path ----
        bool valid = lane < deg;
        int src = valid ? csr[beg + lane] : 0;
        float e = valid ? lrelu(as_v[src] + adi) : -1e30f;
        float m = e;
#pragma unroll
        for (int o = 32; o > 0; o >>= 1) m = fmaxf(m, __shfl_xor(m, o));
        float w = valid ? __expf(e - m) : 0.f;
        float s = w;
#pragma unroll
        for (int o = 32; o > 0; o >>= 1) s += __shfl_xor(s, o);
        inv = 1.0f / s;
        for (int b = 0; b < deg; b += 4) {
            int idx = b + quarter;                 // <= 63 always
            float wv = __shfl(w, idx);
            int sv = __shfl(src, idx);
            uint4 hv = ((const uint4*)hb)[(size_t)sv * 16 + c8];
            acc[0] += wv * __uint_as_float(hv.x << 16);
            acc[1] += wv * __uint_as_float(hv.x & 0xffff0000u);
            acc[2] += wv * __uint_as_float(hv.y << 16);
            acc[3] += wv * __uint_as_float(hv.y & 0xffff0000u);
            acc[4] += wv * __uint_as_float(hv.z << 16);
            acc[5] += wv * __uint_as_float(hv.z & 0xffff0000u);
            acc[6] += wv * __uint_as_float(hv.w << 16);
            acc[7] += wv * __uint_as_float(hv.w & 0xffff0000u);
        }
    } else {
        // ---- fallback (rare): wedge-array path ----
        float m = -1e30f;
        for (int p = beg + lane; p < end; p += 64) {
            float e = lrelu(as_v[csr[p]] + adi);
            wedge[p] = e;
            m = fmaxf(m, e);
        }
#pragma unroll
        for (int o = 32; o > 0; o >>= 1) m = fmaxf(m, __shfl_xor(m, o));
        float s = 0.f;
        for (int p = beg + lane; p < end; p += 64) {
            float wv = __expf(wedge[p] - m);
            wedge[p] = wv;
            s += wv;
        }
#pragma unroll
        for (int o = 32; o > 0; o >>= 1) s += __shfl_xor(s, o);
        inv = 1.0f / s;
        for (int p = beg; p < end; p += 4) {
            int pp = p + quarter;
            float wv; int sv;
            if (pp < end) { wv = wedge[pp]; sv = csr[pp]; }
            else { wv = 0.f; sv = 0; }
            uint4 hv = ((const uint4*)hb)[(size_t)sv * 16 + c8];
            acc[0] += wv * __uint_as_float(hv.x << 16);
            acc[1] += wv * __uint_as_float(hv.x & 0xffff0000u);
            acc[2] += wv * __uint_as_float(hv.y << 16);
            acc[3] += wv * __uint_as_float(hv.y & 0xffff0000u);
            acc[4] += wv * __uint_as_float(hv.z << 16);
            acc[5] += wv * __uint_as_float(hv.z & 0xffff0000u);
            acc[6] += wv * __uint_as_float(hv.w << 16);
            acc[7] += wv * __uint_as_float(hv.w & 0xffff0000u);
        }
    }
#pragma unroll
    for (int k = 0; k < 8; ++k) {
        acc[k] += __shfl_xor(acc[k], 16);
        acc[k] += __shfl_xor(acc[k], 32);
    }
    if (quarter == 0) {
        const float4 bv0 = ((const float4*)bias)[c8 * 2];
        const float4 bv1 = ((const float4*)bias)[c8 * 2 + 1];
        float o0 = seluf(acc[0] * inv + bv0.x);
        float o1 = seluf(acc[1] * inv + bv0.y);
        float o2 = seluf(acc[2] * inv + bv0.z);
        float o3 = seluf(acc[3] * inv + bv0.w);
        float o4 = seluf(acc[4] * inv + bv1.x);
        float o5 = seluf(acc[5] * inv + bv1.y);
        float o6 = seluf(acc[6] * inv + bv1.z);
        float o7 = seluf(acc[7] * inv + bv1.w);
        uint4 ov;
        ov.x = pk(o0, o1);
        ov.y = pk(o2, o3);
        ov.z = pk(o4, o5);
        ov.w = pk(o6, o7);
        ((uint4*)out)[(size_t)gw * 16 + c8] = ov;
    }
}

// ---- global mean pool (batch is sorted, bf16 input, fp32 output) -----------

__device__ int lower_bound_dev(const int* a, int n, int key) {
    int lo = 0, hi = n;
    while (lo < hi) {
        int mid = (lo + hi) >> 1;
        if (a[mid] < key) lo = mid + 1; else hi = mid;
    }
    return lo;
}

__global__ __launch_bounds__(256) void k_pool(const __hip_bfloat16* __restrict__ x,
                                              const int* __restrict__ batchv,
                                              float* __restrict__ outp, int n) {
    int g = blockIdx.x;
    int lo = lower_bound_dev(batchv, n, g);
    int hi = lower_bound_dev(batchv, n, g + 1);
    int lane = threadIdx.x & 63, wv = threadIdx.x >> 6;
    float sx = 0.f, sy = 0.f;
    for (int i = lo + wv; i < hi; i += 4) {
        unsigned u = ((const unsigned*)x)[(size_t)i * 64 + lane];
        sx += __uint_as_float(u << 16);
        sy += __uint_as_float(u & 0xffff0000u);
    }
    __shared__ float2 red[4][64];
    red[wv][lane] = make_float2(sx, sy);
    __syncthreads();
    if (wv == 0) {
        float2 a = red[0][lane], b = red[1][lane], c = red[2][lane], d = red[3][lane];
        int cntv = hi - lo; if (cntv < 1) cntv = 1;
        float inv = 1.0f / (float)cntv;
        outp[(size_t)g * CH + 2 * lane] = (a.x + b.x + c.x + d.x) * inv;
        outp[(size_t)g * CH + 2 * lane + 1] = (a.y + b.y + c.y + d.y) * inv;
    }
}

// ---- orchestration ---------------------------------------------------------

extern "C" void kernel_launch(void* const* d_in, const int* in_sizes, int n_in,
                              void* d_out, int out_size, void* d_ws, size_t ws_size,
                              hipStream_t stream) {
    const float* u   = (const float*)d_in[0];
    const float* W1  = (const float*)d_in[1];
    const float* as1 = (const float*)d_in[2];
    const float* ad1 = (const float*)d_in[3];
    const float* b1  = (const float*)d_in[4];
    const float* W2  = (const float*)d_in[5];
    const float* as2 = (const float*)d_in[6];
    const float* ad2 = (const float*)d_in[7];
    const float* b2  = (const float*)d_in[8];
    const int* ei    = (const int*)d_in[9];
    const int* batchv= (const int*)d_in[10];

    const int N = in_sizes[0] / CH;
    const int E = in_sizes[9] / 2;
    const int M = E + N;
    const int NP = (N + PSIZE - 1) >> PSHIFT;

    char* p = (char*)d_ws;
    auto alloc = [&](size_t bytes) {
        char* r = p;
        p += (bytes + 255) & ~(size_t)255;
        return r;
    };
    int*   pfill  = (int*)alloc((size_t)NP * 4);
    size_t zbytes = (size_t)(p - (char*)d_ws);      // zero pfill
    int*   rowptr = (int*)alloc((size_t)(N + 1) * 4);
    int*   pbase  = (int*)alloc((size_t)(NP + 1) * 4);
    int*   csr    = (int*)alloc((size_t)M * 4);
    float* wedge  = (float*)alloc((size_t)M * 4);   // fallback path only
    float* asv    = (float*)alloc((size_t)N * 4);
    float* adv    = (float*)alloc((size_t)N * 4);
    // staged aliases hbuf: staged is fully consumed by k_build before the
    // first k_gemm3 writes hbuf.
    size_t hbytes = (size_t)N * CH * 2;
    size_t sbytes = (size_t)NP * PCAP * 8;
    char*  hs     = alloc(hbytes > sbytes ? hbytes : sbytes);
    __hip_bfloat16* hbuf = (__hip_bfloat16*)hs;
    unsigned long long* staged = (unsigned long long*)hs;
    __hip_bfloat16* x2 = (__hip_bfloat16*)alloc((size_t)N * CH * 2);

    hipMemsetAsync(d_ws, 0, zbytes, stream);

    k_part<<<(E + CHUNK - 1) / CHUNK, 256, 0, stream>>>(ei, pfill, staged, E, NP);
    k_ptop<<<1, 128, 0, stream>>>(pfill, pbase, rowptr, N, E, NP);
    k_build<<<NP, 1024, 0, stream>>>(staged, pfill, pbase, rowptr, csr, N);

    const int gblocks = (N + 127) / 128;

    // layer 1 (fp32 input)
    k_gemm3<float><<<gblocks, 256, 0, stream>>>(u, W1, as1, ad1, hbuf, asv, adv, N);
    k_fused_agg<<<(N * 64 + 255) / 256, 256, 0, stream>>>(rowptr, csr, asv, adv, wedge, hbuf, b1, x2, N);

    // layer 2 (bf16 input)
    k_gemm3<__hip_bfloat16><<<gblocks, 256, 0, stream>>>(x2, W2, as2, ad2, hbuf, asv, adv, N);
    k_fused_agg<<<(N * 64 + 255) / 256, 256, 0, stream>>>(rowptr, csr, asv, adv, wedge, hbuf, b2, x2, N);

    k_pool<<<64, 256, 0, stream>>>(x2, batchv, (float*)d_out, N);
}

// Round 10
// 221.963 us; speedup vs baseline: 3.6308x; 1.2063x over previous
//
#include <hip/hip_runtime.h>
#include <hip/hip_bf16.h>
#include <math.h>

#define CH 128
#define PSHIFT 9              // 512 nodes per partition
#define PSIZE (1 << PSHIFT)
#define CHUNK 2048            // edges per block in k_part
#define EPT 8                 // edges per thread (256 * 8 = 2048)
#define MAXP 128              // max partitions (N <= 65536)
#define PCAP 24576            // staging capacity per partition (mean 16384 + 64 sigma)
#define PS 8                  // pool slices per graph

typedef __attribute__((ext_vector_type(8))) short short8;
typedef __attribute__((ext_vector_type(4))) float f32x4;

__device__ __forceinline__ float seluf(float x) {
    const float scale = 1.0507009873554804934193349852946f;
    const float alpha = 1.6732632423543772848170429916717f;
    return x > 0.0f ? scale * x : scale * alpha * (__expf(x) - 1.0f);
}

__device__ __forceinline__ float lrelu(float x) {
    return x > 0.0f ? x : 0.2f * x;
}

__device__ __forceinline__ short bfc(float f) {
    union { __hip_bfloat16 b; short s; } u;
    u.b = __float2bfloat16(f);
    return u.s;
}

__device__ __forceinline__ unsigned pk(float lo, float hi) {
    return ((unsigned)(unsigned short)bfc(hi) << 16) | (unsigned short)bfc(lo);
}

// ---- CSR build -------------------------------------------------------------

__global__ __launch_bounds__(256) void k_part(const int* __restrict__ ei,
                                              int* __restrict__ pfill,
                                              unsigned long long* __restrict__ staged,
                                              int E, int NP) {
    __shared__ int hist[MAXP];
    __shared__ int base[MAXP];
    const int tid = threadIdx.x;
    const int j0 = blockIdx.x * CHUNK;
    for (int i = tid; i < NP; i += 256) hist[i] = 0;
    __syncthreads();
    int part[EPT], rank[EPT];
    unsigned long long rec[EPT];
#pragma unroll
    for (int e = 0; e < EPT; ++e) {
        int j = j0 + e * 256 + tid;
        part[e] = -1;
        if (j < E) {
            int s = ei[j], d = ei[E + j];
            part[e] = d >> PSHIFT;
            rec[e] = ((unsigned long long)(unsigned)d << 32) | (unsigned)s;
            rank[e] = atomicAdd(&hist[part[e]], 1);
        }
    }
    __syncthreads();
    for (int i = tid; i < NP; i += 256)
        base[i] = hist[i] ? atomicAdd(&pfill[i], hist[i]) : 0;
    __syncthreads();
#pragma unroll
    for (int e = 0; e < EPT; ++e)
        if (part[e] >= 0)
            staged[(size_t)part[e] * PCAP + base[part[e]] + rank[e]] = rec[e];
}

__global__ __launch_bounds__(128) void k_ptop(const int* __restrict__ pfill,
                                              int* __restrict__ pbase,
                                              int* __restrict__ rowptr,
                                              int n, int E, int NP) {
    __shared__ int sb[128];
    int t = threadIdx.x;
    int v = (t < NP) ? pfill[t] : 0;
    sb[t] = v;
    __syncthreads();
    for (int off = 1; off < 128; off <<= 1) {
        int u = (t >= off) ? sb[t - off] : 0;
        __syncthreads();
        sb[t] += u;
        __syncthreads();
    }
    if (t < NP) pbase[t] = sb[t] - v;       // exclusive prefix of edge counts
    if (t == NP - 1) {
        pbase[NP] = sb[t];                   // == E
        rowptr[n] = E + n;
    }
}

__global__ __launch_bounds__(1024) void k_build(
    const unsigned long long* __restrict__ staged, const int* __restrict__ pfill,
    const int* __restrict__ pbase, int* __restrict__ rowptr, int* __restrict__ csr,
    int n) {
    const int p = blockIdx.x;
    const int d0 = p << PSHIFT;
    __shared__ int lcnt[PSIZE];
    __shared__ int lrow[PSIZE];
    __shared__ int sc[PSIZE];
    const int tid = threadIdx.x;
    if (tid < PSIZE) lcnt[tid] = 0;
    __syncthreads();
    const size_t rbeg = (size_t)p * PCAP;
    const size_t rend = rbeg + pfill[p];
    const int rb = pbase[p] + d0;        // rowptr base for this partition
    for (size_t r = rbeg + tid; r < rend; r += 1024)
        atomicAdd(&lcnt[(int)(staged[r] >> 32) - d0], 1);
    __syncthreads();
    int myv = 0;
    if (tid < PSIZE) {
        myv = (d0 + tid < n) ? lcnt[tid] + 1 : 0;
        sc[tid] = myv;
    }
    __syncthreads();
    for (int off = 1; off < PSIZE; off <<= 1) {
        int u = 0;
        if (tid < PSIZE && tid >= off) u = sc[tid - off];
        __syncthreads();
        if (tid < PSIZE) sc[tid] += u;
        __syncthreads();
    }
    if (tid < PSIZE && d0 + tid < n) {
        int rp = rb + sc[tid] - myv;     // exclusive prefix
        lrow[tid] = rp;
        rowptr[d0 + tid] = rp;
        csr[rp] = d0 + tid;              // self loop
        lcnt[tid] = 0;                   // reuse as fill counter
    }
    __syncthreads();
    for (size_t r = rbeg + tid; r < rend; r += 1024) {
        unsigned long long v = staged[r];
        int d = (int)(v >> 32), s = (int)(v & 0xffffffffu);
        int pos = lrow[d - d0] + 1 + atomicAdd(&lcnt[d - d0], 1);
        csr[pos] = s;
    }
}

// ---- GEMM v3: MFMA bf16. h = x@W, fused attention dots ---------------------

template <typename T>
__global__ __launch_bounds__(256) void k_gemm3(
    const T* __restrict__ x, const float* __restrict__ W,
    const float* __restrict__ a_s, const float* __restrict__ a_d,
    __hip_bfloat16* __restrict__ hb, float* __restrict__ as_o,
    float* __restrict__ ad_o, int n) {
    __shared__ short WB[4 * 8 * 64 * 8];   // 16384 bf16 = 32 KB
    const int tid = threadIdx.x;
    for (int i = tid; i < CH * CH; i += 256) {
        int k = i >> 7, c = i & 127;
        int kb = k >> 5, kk = k & 31;
        int t = c >> 4;
        int ln = (c & 15) | ((kk >> 3) << 4);
        int j = kk & 7;
        WB[(((kb << 3) + t) << 9) + (ln << 3) + j] = bfc(W[i]);
    }
    __syncthreads();
    const int lane = tid & 63;
    const int wid = tid >> 6;
    const int l15 = lane & 15;
    const int lhi = lane >> 4;
    float asl[8], adl[8];
#pragma unroll
    for (int t = 0; t < 8; ++t) {
        asl[t] = a_s[t * 16 + l15];
        adl[t] = a_d[t * 16 + l15];
    }
#pragma unroll
    for (int s = 0; s < 2; ++s) {
        int r0 = blockIdx.x * 128 + s * 64 + wid * 16;
        if (r0 >= n) break;
        int ar = r0 + l15; if (ar >= n) ar = n - 1;
        const T* xr = x + (size_t)ar * CH + lhi * 8;
        f32x4 acc[8];
#pragma unroll
        for (int t = 0; t < 8; ++t) acc[t] = (f32x4){0.f, 0.f, 0.f, 0.f};
#pragma unroll
        for (int kb = 0; kb < 4; ++kb) {
            short8 af;
            if constexpr (sizeof(T) == 4) {
                float4 xa = *(const float4*)(xr + kb * 32);
                float4 xb = *(const float4*)(xr + kb * 32 + 4);
                af[0] = bfc(xa.x); af[1] = bfc(xa.y); af[2] = bfc(xa.z); af[3] = bfc(xa.w);
                af[4] = bfc(xb.x); af[5] = bfc(xb.y); af[6] = bfc(xb.z); af[7] = bfc(xb.w);
            } else {
                af = *(const short8*)(xr + kb * 32);
            }
#pragma unroll
            for (int t = 0; t < 8; ++t) {
                short8 bv = ((const short8*)WB)[(((kb << 3) + t) << 6) | lane];
                acc[t] = __builtin_amdgcn_mfma_f32_16x16x32_bf16(af, bv, acc[t], 0, 0, 0);
            }
        }
        float pa[4] = {0.f, 0.f, 0.f, 0.f}, pd[4] = {0.f, 0.f, 0.f, 0.f};
#pragma unroll
        for (int t = 0; t < 8; ++t) {
#pragma unroll
            for (int q = 0; q < 4; ++q) {
                int row = r0 + lhi * 4 + q;
                if (row < n)
                    hb[(size_t)row * CH + t * 16 + l15] = __float2bfloat16(acc[t][q]);
                pa[q] += acc[t][q] * asl[t];
                pd[q] += acc[t][q] * adl[t];
            }
        }
#pragma unroll
        for (int q = 0; q < 4; ++q) {
#pragma unroll
            for (int o = 1; o < 16; o <<= 1) {
                pa[q] += __shfl_xor(pa[q], o);
                pd[q] += __shfl_xor(pd[q], o);
            }
        }
        if (l15 == 0) {
#pragma unroll
            for (int q = 0; q < 4; ++q) {
                int row = r0 + lhi * 4 + q;
                if (row < n) { as_o[row] = pa[q]; ad_o[row] = pd[q]; }
            }
        }
    }
}

// ---- fused softmax + aggregation: one wave per node, bf16 out --------------

__global__ __launch_bounds__(256) void k_fused_agg(
    const int* __restrict__ rowptr, const int* __restrict__ csr,
    const float* __restrict__ as_v, const float* __restrict__ ad_v,
    float* __restrict__ wedge, const __hip_bfloat16* __restrict__ hb,
    const float* __restrict__ bias, __hip_bfloat16* __restrict__ out, int n) {
    int gw = (int)((blockIdx.x * (size_t)blockDim.x + threadIdx.x) >> 6);
    int lane = threadIdx.x & 63;
    if (gw >= n) return;
    int beg = rowptr[gw], end = rowptr[gw + 1];
    int deg = end - beg;
    float adi = ad_v[gw];

    const int quarter = lane >> 4;     // edge sub-slot 0..3
    const int c8 = lane & 15;          // 8-channel block
    float acc[8];
#pragma unroll
    for (int k = 0; k < 8; ++k) acc[k] = 0.f;
    float inv;

    if (deg <= 64) {
        bool valid = lane < deg;
        int src = valid ? csr[beg + lane] : 0;
        float e = valid ? lrelu(as_v[src] + adi) : -1e30f;
        float m = e;
#pragma unroll
        for (int o = 32; o > 0; o >>= 1) m = fmaxf(m, __shfl_xor(m, o));
        float w = valid ? __expf(e - m) : 0.f;
        float s = w;
#pragma unroll
        for (int o = 32; o > 0; o >>= 1) s += __shfl_xor(s, o);
        inv = 1.0f / s;
        for (int b = 0; b < deg; b += 4) {
            int idx = b + quarter;                 // <= 63 always
            float wv = __shfl(w, idx);
            int sv = __shfl(src, idx);
            uint4 hv = ((const uint4*)hb)[(size_t)sv * 16 + c8];
            acc[0] += wv * __uint_as_float(hv.x << 16);
            acc[1] += wv * __uint_as_float(hv.x & 0xffff0000u);
            acc[2] += wv * __uint_as_float(hv.y << 16);
            acc[3] += wv * __uint_as_float(hv.y & 0xffff0000u);
            acc[4] += wv * __uint_as_float(hv.z << 16);
            acc[5] += wv * __uint_as_float(hv.z & 0xffff0000u);
            acc[6] += wv * __uint_as_float(hv.w << 16);
            acc[7] += wv * __uint_as_float(hv.w & 0xffff0000u);
        }
    } else {
        float m = -1e30f;
        for (int p = beg + lane; p < end; p += 64) {
            float e = lrelu(as_v[csr[p]] + adi);
            wedge[p] = e;
            m = fmaxf(m, e);
        }
#pragma unroll
        for (int o = 32; o > 0; o >>= 1) m = fmaxf(m, __shfl_xor(m, o));
        float s = 0.f;
        for (int p = beg + lane; p < end; p += 64) {
            float wv = __expf(wedge[p] - m);
            wedge[p] = wv;
            s += wv;
        }
#pragma unroll
        for (int o = 32; o > 0; o >>= 1) s += __shfl_xor(s, o);
        inv = 1.0f / s;
        for (int p = beg; p < end; p += 4) {
            int pp = p + quarter;
            float wv; int sv;
            if (pp < end) { wv = wedge[pp]; sv = csr[pp]; }
            else { wv = 0.f; sv = 0; }
            uint4 hv = ((const uint4*)hb)[(size_t)sv * 16 + c8];
            acc[0] += wv * __uint_as_float(hv.x << 16);
            acc[1] += wv * __uint_as_float(hv.x & 0xffff0000u);
            acc[2] += wv * __uint_as_float(hv.y << 16);
            acc[3] += wv * __uint_as_float(hv.y & 0xffff0000u);
            acc[4] += wv * __uint_as_float(hv.z << 16);
            acc[5] += wv * __uint_as_float(hv.z & 0xffff0000u);
            acc[6] += wv * __uint_as_float(hv.w << 16);
            acc[7] += wv * __uint_as_float(hv.w & 0xffff0000u);
        }
    }
#pragma unroll
    for (int k = 0; k < 8; ++k) {
        acc[k] += __shfl_xor(acc[k], 16);
        acc[k] += __shfl_xor(acc[k], 32);
    }
    if (quarter == 0) {
        const float4 bv0 = ((const float4*)bias)[c8 * 2];
        const float4 bv1 = ((const float4*)bias)[c8 * 2 + 1];
        float o0 = seluf(acc[0] * inv + bv0.x);
        float o1 = seluf(acc[1] * inv + bv0.y);
        float o2 = seluf(acc[2] * inv + bv0.z);
        float o3 = seluf(acc[3] * inv + bv0.w);
        float o4 = seluf(acc[4] * inv + bv1.x);
        float o5 = seluf(acc[5] * inv + bv1.y);
        float o6 = seluf(acc[6] * inv + bv1.z);
        float o7 = seluf(acc[7] * inv + bv1.w);
        uint4 ov;
        ov.x = pk(o0, o1);
        ov.y = pk(o2, o3);
        ov.z = pk(o4, o5);
        ov.w = pk(o6, o7);
        ((uint4*)out)[(size_t)gw * 16 + c8] = ov;
    }
}

// ---- global mean pool: two-stage deterministic reduction -------------------

__device__ int lower_bound_dev(const int* a, int n, int key) {
    int lo = 0, hi = n;
    while (lo < hi) {
        int mid = (lo + hi) >> 1;
        if (a[mid] < key) lo = mid + 1; else hi = mid;
    }
    return lo;
}

// Stage 1: 64 graphs x PS slices; block (g,s) covers row-slots s*4+w stride 32.
__global__ __launch_bounds__(256) void k_pool1(const __hip_bfloat16* __restrict__ x,
                                               const int* __restrict__ batchv,
                                               float* __restrict__ part, int n) {
    int g = blockIdx.x >> 3, s = blockIdx.x & (PS - 1);
    int lo = lower_bound_dev(batchv, n, g);
    int hi = lower_bound_dev(batchv, n, g + 1);
    int lane = threadIdx.x & 63, wv = threadIdx.x >> 6;
    int slot = s * 4 + wv;             // 0..31
    float sx0 = 0.f, sy0 = 0.f, sx1 = 0.f, sy1 = 0.f;
    int i = lo + slot;
    for (; i + 32 < hi; i += 64) {
        unsigned u0 = ((const unsigned*)x)[(size_t)i * 64 + lane];
        unsigned u1 = ((const unsigned*)x)[(size_t)(i + 32) * 64 + lane];
        sx0 += __uint_as_float(u0 << 16);
        sy0 += __uint_as_float(u0 & 0xffff0000u);
        sx1 += __uint_as_float(u1 << 16);
        sy1 += __uint_as_float(u1 & 0xffff0000u);
    }
    if (i < hi) {
        unsigned u0 = ((const unsigned*)x)[(size_t)i * 64 + lane];
        sx0 += __uint_as_float(u0 << 16);
        sy0 += __uint_as_float(u0 & 0xffff0000u);
    }
    __shared__ float2 red[4][64];
    red[wv][lane] = make_float2(sx0 + sx1, sy0 + sy1);
    __syncthreads();
    if (wv == 0) {
        float2 a = red[0][lane], b = red[1][lane], c = red[2][lane], d = red[3][lane];
        float* pp = part + ((size_t)(g * PS + s)) * CH;
        pp[2 * lane] = a.x + b.x + c.x + d.x;
        pp[2 * lane + 1] = a.y + b.y + c.y + d.y;
    }
}

// Stage 2: combine PS slices, divide by count.
__global__ __launch_bounds__(128) void k_pool2(const float* __restrict__ part,
                                               const int* __restrict__ batchv,
                                               float* __restrict__ outp, int n) {
    int g = blockIdx.x, t = threadIdx.x;
    int lo = lower_bound_dev(batchv, n, g);
    int hi = lower_bound_dev(batchv, n, g + 1);
    float v = 0.f;
#pragma unroll
    for (int s = 0; s < PS; ++s) v += part[((size_t)(g * PS + s)) * CH + t];
    int cnt = hi - lo; if (cnt < 1) cnt = 1;
    outp[(size_t)g * CH + t] = v / (float)cnt;
}

// ---- orchestration ---------------------------------------------------------

extern "C" void kernel_launch(void* const* d_in, const int* in_sizes, int n_in,
                              void* d_out, int out_size, void* d_ws, size_t ws_size,
                              hipStream_t stream) {
    const float* u   = (const float*)d_in[0];
    const float* W1  = (const float*)d_in[1];
    const float* as1 = (const float*)d_in[2];
    const float* ad1 = (const float*)d_in[3];
    const float* b1  = (const float*)d_in[4];
    const float* W2  = (const float*)d_in[5];
    const float* as2 = (const float*)d_in[6];
    const float* ad2 = (const float*)d_in[7];
    const float* b2  = (const float*)d_in[8];
    const int* ei    = (const int*)d_in[9];
    const int* batchv= (const int*)d_in[10];

    const int N = in_sizes[0] / CH;
    const int E = in_sizes[9] / 2;
    const int M = E + N;
    const int NP = (N + PSIZE - 1) >> PSHIFT;
    const int G = out_size / CH;

    char* p = (char*)d_ws;
    auto alloc = [&](size_t bytes) {
        char* r = p;
        p += (bytes + 255) & ~(size_t)255;
        return r;
    };
    int*   pfill  = (int*)alloc((size_t)NP * 4);
    size_t zbytes = (size_t)(p - (char*)d_ws);      // zero pfill
    int*   rowptr = (int*)alloc((size_t)(N + 1) * 4);
    int*   pbase  = (int*)alloc((size_t)(NP + 1) * 4);
    int*   csr    = (int*)alloc((size_t)M * 4);
    float* wedge  = (float*)alloc((size_t)M * 4);   // fallback path only
    float* asv    = (float*)alloc((size_t)N * 4);
    float* adv    = (float*)alloc((size_t)N * 4);
    float* ppart  = (float*)alloc((size_t)G * PS * CH * 4);
    // staged aliases hbuf: staged is fully consumed by k_build before the
    // first k_gemm3 writes hbuf.
    size_t hbytes = (size_t)N * CH * 2;
    size_t sbytes = (size_t)NP * PCAP * 8;
    char*  hs     = alloc(hbytes > sbytes ? hbytes : sbytes);
    __hip_bfloat16* hbuf = (__hip_bfloat16*)hs;
    unsigned long long* staged = (unsigned long long*)hs;
    __hip_bfloat16* x2 = (__hip_bfloat16*)alloc((size_t)N * CH * 2);

    hipMemsetAsync(d_ws, 0, zbytes, stream);

    k_part<<<(E + CHUNK - 1) / CHUNK, 256, 0, stream>>>(ei, pfill, staged, E, NP);
    k_ptop<<<1, 128, 0, stream>>>(pfill, pbase, rowptr, N, E, NP);
    k_build<<<NP, 1024, 0, stream>>>(staged, pfill, pbase, rowptr, csr, N);

    const int gblocks = (N + 127) / 128;

    // layer 1 (fp32 input)
    k_gemm3<float><<<gblocks, 256, 0, stream>>>(u, W1, as1, ad1, hbuf, asv, adv, N);
    k_fused_agg<<<(N * 64 + 255) / 256, 256, 0, stream>>>(rowptr, csr, asv, adv, wedge, hbuf, b1, x2, N);

    // layer 2 (bf16 input)
    k_gemm3<__hip_bfloat16><<<gblocks, 256, 0, stream>>>(x2, W2, as2, ad2, hbuf, asv, adv, N);
    k_fused_agg<<<(N * 64 + 255) / 256, 256, 0, stream>>>(rowptr, csr, asv, adv, wedge, hbuf, b2, x2, N);

    k_pool1<<<G * PS, 256, 0, stream>>>(x2, batchv, ppart, N);
    k_pool2<<<G, 128, 0, stream>>>(ppart, batchv, (float*)d_out, N);
}

// Round 11
// 208.095 us; speedup vs baseline: 3.8728x; 1.0666x over previous
//
#include <hip/hip_runtime.h>
#include <hip/hip_bf16.h>
#include <math.h>

#define CH 128
#define PSHIFT 8              // 256 nodes per partition
#define PSIZE (1 << PSHIFT)
#define CHUNK 2048            // edges per block in k_part
#define EPT 8                 // edges per thread (256 * 8 = 2048)
#define MAXP 256              // max partitions
#define PCAP 12288            // staging capacity per partition (mean ~8163 + huge slack)
#define PS 8                  // pool slices per graph

typedef __attribute__((ext_vector_type(8))) short short8;
typedef __attribute__((ext_vector_type(4))) float f32x4;
typedef __attribute__((ext_vector_type(2))) float f32x2;

__device__ __forceinline__ float seluf(float x) {
    const float scale = 1.0507009873554804934193349852946f;
    const float alpha = 1.6732632423543772848170429916717f;
    return x > 0.0f ? scale * x : scale * alpha * (__expf(x) - 1.0f);
}

__device__ __forceinline__ float lrelu(float x) {
    return x > 0.0f ? x : 0.2f * x;
}

__device__ __forceinline__ short bfc(float f) {
    union { __hip_bfloat16 b; short s; } u;
    u.b = __float2bfloat16(f);
    return u.s;
}

__device__ __forceinline__ unsigned pk(float lo, float hi) {
    return ((unsigned)(unsigned short)bfc(hi) << 16) | (unsigned short)bfc(lo);
}

// ---- CSR build pass A ------------------------------------------------------

__global__ __launch_bounds__(256) void k_part(const int* __restrict__ ei,
                                              int* __restrict__ pfill,
                                              unsigned long long* __restrict__ staged,
                                              int E, int NP) {
    __shared__ int hist[MAXP];
    __shared__ int base[MAXP];
    const int tid = threadIdx.x;
    const int j0 = blockIdx.x * CHUNK;
    for (int i = tid; i < NP; i += 256) hist[i] = 0;
    __syncthreads();
    int part[EPT], rank[EPT];
    unsigned long long rec[EPT];
#pragma unroll
    for (int e = 0; e < EPT; ++e) {
        int j = j0 + e * 256 + tid;
        part[e] = -1;
        if (j < E) {
            int s = ei[j], d = ei[E + j];
            part[e] = d >> PSHIFT;
            rec[e] = ((unsigned long long)(unsigned)d << 32) | (unsigned)s;
            rank[e] = atomicAdd(&hist[part[e]], 1);
        }
    }
    __syncthreads();
    for (int i = tid; i < NP; i += 256)
        base[i] = hist[i] ? atomicAdd(&pfill[i], hist[i]) : 0;
    __syncthreads();
#pragma unroll
    for (int e = 0; e < EPT; ++e)
        if (part[e] >= 0)
            staged[(size_t)part[e] * PCAP + base[part[e]] + rank[e]] = rec[e];
}

// ---- fat kernel: CSR build pass B (blocks < NP) || GEMM layer 1 (rest) -----
// Build: per-partition node histogram + scan + scatter in LDS; partition
// prefix computed in-block (no k_ptop). GEMM: MFMA bf16, W in LDS.

__global__ __launch_bounds__(256) void k_fat(
    const unsigned long long* __restrict__ staged, const int* __restrict__ pfill,
    int* __restrict__ rowptr, int* __restrict__ csr, int n, int E, int NP,
    const float* __restrict__ x, const float* __restrict__ W,
    const float* __restrict__ a_s, const float* __restrict__ a_d,
    __hip_bfloat16* __restrict__ hb, float* __restrict__ as_o,
    float* __restrict__ ad_o) {
    __shared__ __align__(16) char sm[32768];
    const int tid = threadIdx.x;

    if ((int)blockIdx.x < NP) {
        // ---------------- build path ----------------
        int* lcnt = (int*)sm;            // [256]
        int* lrow = lcnt + PSIZE;        // [256]
        int* sc   = lrow + PSIZE;        // [256]
        int* psc  = sc + PSIZE;          // [256]
        const int p = blockIdx.x;
        const int d0 = p << PSHIFT;
        psc[tid] = (tid < NP) ? pfill[tid] : 0;
        lcnt[tid] = 0;
        __syncthreads();
        for (int off = 1; off < 256; off <<= 1) {
            int v = (tid >= off) ? psc[tid - off] : 0;
            __syncthreads();
            psc[tid] += v;
            __syncthreads();
        }
        const int pbase = psc[p] - pfill[p];   // exclusive prefix of edge counts
        const size_t rbeg = (size_t)p * PCAP;
        const size_t rend = rbeg + pfill[p];
        const int rb = pbase + d0;
        for (size_t r = rbeg + tid; r < rend; r += 256)
            atomicAdd(&lcnt[(int)(staged[r] >> 32) - d0], 1);
        __syncthreads();
        int myv = (d0 + tid < n) ? lcnt[tid] + 1 : 0;
        sc[tid] = myv;
        __syncthreads();
        for (int off = 1; off < 256; off <<= 1) {
            int v = (tid >= off) ? sc[tid - off] : 0;
            __syncthreads();
            sc[tid] += v;
            __syncthreads();
        }
        if (d0 + tid < n) {
            int rp = rb + sc[tid] - myv;
            lrow[tid] = rp;
            rowptr[d0 + tid] = rp;
            csr[rp] = d0 + tid;              // self loop
            lcnt[tid] = 0;                   // reuse as fill counter
        }
        if (p == 0 && tid == 0) rowptr[n] = E + n;
        __syncthreads();
        for (size_t r = rbeg + tid; r < rend; r += 256) {
            unsigned long long v = staged[r];
            int d = (int)(v >> 32), s = (int)(v & 0xffffffffu);
            int pos = lrow[d - d0] + 1 + atomicAdd(&lcnt[d - d0], 1);
            csr[pos] = s;
        }
        return;
    }

    // ---------------- gemm path (layer 1, fp32 input) ----------------
    short* WB = (short*)sm;                  // 16384 bf16 = 32 KB
    for (int i = tid; i < CH * CH; i += 256) {
        int k = i >> 7, c = i & 127;
        int kb = k >> 5, kk = k & 31;
        int t = c >> 4;
        int ln = (c & 15) | ((kk >> 3) << 4);
        int j = kk & 7;
        WB[(((kb << 3) + t) << 9) + (ln << 3) + j] = bfc(W[i]);
    }
    __syncthreads();
    const int bid = blockIdx.x - NP;
    const int lane = tid & 63;
    const int wid = tid >> 6;
    const int l15 = lane & 15;
    const int lhi = lane >> 4;
    float asl[8], adl[8];
#pragma unroll
    for (int t = 0; t < 8; ++t) {
        asl[t] = a_s[t * 16 + l15];
        adl[t] = a_d[t * 16 + l15];
    }
#pragma unroll
    for (int s = 0; s < 2; ++s) {
        int r0 = bid * 128 + s * 64 + wid * 16;
        if (r0 >= n) break;
        int ar = r0 + l15; if (ar >= n) ar = n - 1;
        const float* xr = x + (size_t)ar * CH + lhi * 8;
        f32x4 acc[8];
#pragma unroll
        for (int t = 0; t < 8; ++t) acc[t] = (f32x4){0.f, 0.f, 0.f, 0.f};
#pragma unroll
        for (int kb = 0; kb < 4; ++kb) {
            float4 xa = *(const float4*)(xr + kb * 32);
            float4 xb = *(const float4*)(xr + kb * 32 + 4);
            short8 af;
            af[0] = bfc(xa.x); af[1] = bfc(xa.y); af[2] = bfc(xa.z); af[3] = bfc(xa.w);
            af[4] = bfc(xb.x); af[5] = bfc(xb.y); af[6] = bfc(xb.z); af[7] = bfc(xb.w);
#pragma unroll
            for (int t = 0; t < 8; ++t) {
                short8 bv = ((const short8*)WB)[(((kb << 3) + t) << 6) | lane];
                acc[t] = __builtin_amdgcn_mfma_f32_16x16x32_bf16(af, bv, acc[t], 0, 0, 0);
            }
        }
        float pa[4] = {0.f, 0.f, 0.f, 0.f}, pd[4] = {0.f, 0.f, 0.f, 0.f};
#pragma unroll
        for (int t = 0; t < 8; ++t) {
#pragma unroll
            for (int q = 0; q < 4; ++q) {
                int row = r0 + lhi * 4 + q;
                if (row < n)
                    hb[(size_t)row * CH + t * 16 + l15] = __float2bfloat16(acc[t][q]);
                pa[q] += acc[t][q] * asl[t];
                pd[q] += acc[t][q] * adl[t];
            }
        }
#pragma unroll
        for (int q = 0; q < 4; ++q) {
#pragma unroll
            for (int o = 1; o < 16; o <<= 1) {
                pa[q] += __shfl_xor(pa[q], o);
                pd[q] += __shfl_xor(pd[q], o);
            }
        }
        if (l15 == 0) {
#pragma unroll
            for (int q = 0; q < 4; ++q) {
                int row = r0 + lhi * 4 + q;
                if (row < n) { as_o[row] = pa[q]; ad_o[row] = pd[q]; }
            }
        }
    }
}

// ---- GEMM v3 (standalone, layer 2 bf16 input) ------------------------------

template <typename T>
__global__ __launch_bounds__(256) void k_gemm3(
    const T* __restrict__ x, const float* __restrict__ W,
    const float* __restrict__ a_s, const float* __restrict__ a_d,
    __hip_bfloat16* __restrict__ hb, float* __restrict__ as_o,
    float* __restrict__ ad_o, int n) {
    __shared__ short WB[4 * 8 * 64 * 8];   // 32 KB
    const int tid = threadIdx.x;
    for (int i = tid; i < CH * CH; i += 256) {
        int k = i >> 7, c = i & 127;
        int kb = k >> 5, kk = k & 31;
        int t = c >> 4;
        int ln = (c & 15) | ((kk >> 3) << 4);
        int j = kk & 7;
        WB[(((kb << 3) + t) << 9) + (ln << 3) + j] = bfc(W[i]);
    }
    __syncthreads();
    const int lane = tid & 63;
    const int wid = tid >> 6;
    const int l15 = lane & 15;
    const int lhi = lane >> 4;
    float asl[8], adl[8];
#pragma unroll
    for (int t = 0; t < 8; ++t) {
        asl[t] = a_s[t * 16 + l15];
        adl[t] = a_d[t * 16 + l15];
    }
#pragma unroll
    for (int s = 0; s < 2; ++s) {
        int r0 = blockIdx.x * 128 + s * 64 + wid * 16;
        if (r0 >= n) break;
        int ar = r0 + l15; if (ar >= n) ar = n - 1;
        const T* xr = x + (size_t)ar * CH + lhi * 8;
        f32x4 acc[8];
#pragma unroll
        for (int t = 0; t < 8; ++t) acc[t] = (f32x4){0.f, 0.f, 0.f, 0.f};
#pragma unroll
        for (int kb = 0; kb < 4; ++kb) {
            short8 af;
            if constexpr (sizeof(T) == 4) {
                float4 xa = *(const float4*)(xr + kb * 32);
                float4 xb = *(const float4*)(xr + kb * 32 + 4);
                af[0] = bfc(xa.x); af[1] = bfc(xa.y); af[2] = bfc(xa.z); af[3] = bfc(xa.w);
                af[4] = bfc(xb.x); af[5] = bfc(xb.y); af[6] = bfc(xb.z); af[7] = bfc(xb.w);
            } else {
                af = *(const short8*)(xr + kb * 32);
            }
#pragma unroll
            for (int t = 0; t < 8; ++t) {
                short8 bv = ((const short8*)WB)[(((kb << 3) + t) << 6) | lane];
                acc[t] = __builtin_amdgcn_mfma_f32_16x16x32_bf16(af, bv, acc[t], 0, 0, 0);
            }
        }
        float pa[4] = {0.f, 0.f, 0.f, 0.f}, pd[4] = {0.f, 0.f, 0.f, 0.f};
#pragma unroll
        for (int t = 0; t < 8; ++t) {
#pragma unroll
            for (int q = 0; q < 4; ++q) {
                int row = r0 + lhi * 4 + q;
                if (row < n)
                    hb[(size_t)row * CH + t * 16 + l15] = __float2bfloat16(acc[t][q]);
                pa[q] += acc[t][q] * asl[t];
                pd[q] += acc[t][q] * adl[t];
            }
        }
#pragma unroll
        for (int q = 0; q < 4; ++q) {
#pragma unroll
            for (int o = 1; o < 16; o <<= 1) {
                pa[q] += __shfl_xor(pa[q], o);
                pd[q] += __shfl_xor(pd[q], o);
            }
        }
        if (l15 == 0) {
#pragma unroll
            for (int q = 0; q < 4; ++q) {
                int row = r0 + lhi * 4 + q;
                if (row < n) { as_o[row] = pa[q]; ad_o[row] = pd[q]; }
            }
        }
    }
}

// ---- fused softmax + aggregation: one wave per node, bf16 out --------------

__global__ __launch_bounds__(256) void k_fused_agg(
    const int* __restrict__ rowptr, const int* __restrict__ csr,
    const float* __restrict__ as_v, const float* __restrict__ ad_v,
    float* __restrict__ wedge, const __hip_bfloat16* __restrict__ hb,
    const float* __restrict__ bias, __hip_bfloat16* __restrict__ out, int n) {
    int gw = (int)((blockIdx.x * (size_t)blockDim.x + threadIdx.x) >> 6);
    int lane = threadIdx.x & 63;
    if (gw >= n) return;
    int beg = rowptr[gw], end = rowptr[gw + 1];
    int deg = end - beg;
    float adi = ad_v[gw];

    const int quarter = lane >> 4;     // edge sub-slot 0..3
    const int c8 = lane & 15;          // 8-channel block
    f32x2 acc2[4];
#pragma unroll
    for (int k = 0; k < 4; ++k) acc2[k] = (f32x2){0.f, 0.f};
    float inv;

    if (deg <= 64) {
        bool valid = lane < deg;
        int src = valid ? csr[beg + lane] : 0;
        float e = valid ? lrelu(as_v[src] + adi) : -1e30f;
        float m = e;
#pragma unroll
        for (int o = 32; o > 0; o >>= 1) m = fmaxf(m, __shfl_xor(m, o));
        float w = valid ? __expf(e - m) : 0.f;
        float s = w;
#pragma unroll
        for (int o = 32; o > 0; o >>= 1) s += __shfl_xor(s, o);
        inv = 1.0f / s;
        for (int b = 0; b < deg; b += 4) {
            int idx = b + quarter;                 // <= 63 always
            float wv = __shfl(w, idx);
            int sv = __shfl(src, idx);
            uint4 hv = ((const uint4*)hb)[(size_t)sv * 16 + c8];
            f32x2 wv2 = (f32x2){wv, wv};
            f32x2 h0, h1, h2, h3;
            h0.x = __uint_as_float(hv.x << 16); h0.y = __uint_as_float(hv.x & 0xffff0000u);
            h1.x = __uint_as_float(hv.y << 16); h1.y = __uint_as_float(hv.y & 0xffff0000u);
            h2.x = __uint_as_float(hv.z << 16); h2.y = __uint_as_float(hv.z & 0xffff0000u);
            h3.x = __uint_as_float(hv.w << 16); h3.y = __uint_as_float(hv.w & 0xffff0000u);
            acc2[0] += wv2 * h0;
            acc2[1] += wv2 * h1;
            acc2[2] += wv2 * h2;
            acc2[3] += wv2 * h3;
        }
    } else {
        float m = -1e30f;
        for (int p = beg + lane; p < end; p += 64) {
            float e = lrelu(as_v[csr[p]] + adi);
            wedge[p] = e;
            m = fmaxf(m, e);
        }
#pragma unroll
        for (int o = 32; o > 0; o >>= 1) m = fmaxf(m, __shfl_xor(m, o));
        float s = 0.f;
        for (int p = beg + lane; p < end; p += 64) {
            float wv = __expf(wedge[p] - m);
            wedge[p] = wv;
            s += wv;
        }
#pragma unroll
        for (int o = 32; o > 0; o >>= 1) s += __shfl_xor(s, o);
        inv = 1.0f / s;
        for (int p = beg; p < end; p += 4) {
            int pp = p + quarter;
            float wv; int sv;
            if (pp < end) { wv = wedge[pp]; sv = csr[pp]; }
            else { wv = 0.f; sv = 0; }
            uint4 hv = ((const uint4*)hb)[(size_t)sv * 16 + c8];
            f32x2 wv2 = (f32x2){wv, wv};
            f32x2 h0, h1, h2, h3;
            h0.x = __uint_as_float(hv.x << 16); h0.y = __uint_as_float(hv.x & 0xffff0000u);
            h1.x = __uint_as_float(hv.y << 16); h1.y = __uint_as_float(hv.y & 0xffff0000u);
            h2.x = __uint_as_float(hv.z << 16); h2.y = __uint_as_float(hv.z & 0xffff0000u);
            h3.x = __uint_as_float(hv.w << 16); h3.y = __uint_as_float(hv.w & 0xffff0000u);
            acc2[0] += wv2 * h0;
            acc2[1] += wv2 * h1;
            acc2[2] += wv2 * h2;
            acc2[3] += wv2 * h3;
        }
    }
#pragma unroll
    for (int k = 0; k < 4; ++k) {
        acc2[k].x += __shfl_xor(acc2[k].x, 16);
        acc2[k].y += __shfl_xor(acc2[k].y, 16);
        acc2[k].x += __shfl_xor(acc2[k].x, 32);
        acc2[k].y += __shfl_xor(acc2[k].y, 32);
    }
    if (quarter == 0) {
        const float4 bv0 = ((const float4*)bias)[c8 * 2];
        const float4 bv1 = ((const float4*)bias)[c8 * 2 + 1];
        float o0 = seluf(acc2[0].x * inv + bv0.x);
        float o1 = seluf(acc2[0].y * inv + bv0.y);
        float o2 = seluf(acc2[1].x * inv + bv0.z);
        float o3 = seluf(acc2[1].y * inv + bv0.w);
        float o4 = seluf(acc2[2].x * inv + bv1.x);
        float o5 = seluf(acc2[2].y * inv + bv1.y);
        float o6 = seluf(acc2[3].x * inv + bv1.z);
        float o7 = seluf(acc2[3].y * inv + bv1.w);
        uint4 ov;
        ov.x = pk(o0, o1);
        ov.y = pk(o2, o3);
        ov.z = pk(o4, o5);
        ov.w = pk(o6, o7);
        ((uint4*)out)[(size_t)gw * 16 + c8] = ov;
    }
}

// ---- global mean pool: two-stage deterministic reduction -------------------

__device__ int lower_bound_dev(const int* a, int n, int key) {
    int lo = 0, hi = n;
    while (lo < hi) {
        int mid = (lo + hi) >> 1;
        if (a[mid] < key) lo = mid + 1; else hi = mid;
    }
    return lo;
}

__global__ __launch_bounds__(256) void k_pool1(const __hip_bfloat16* __restrict__ x,
                                               const int* __restrict__ batchv,
                                               float* __restrict__ part, int n) {
    int g = blockIdx.x >> 3, s = blockIdx.x & (PS - 1);
    int lo = lower_bound_dev(batchv, n, g);
    int hi = lower_bound_dev(batchv, n, g + 1);
    int lane = threadIdx.x & 63, wv = threadIdx.x >> 6;
    int slot = s * 4 + wv;             // 0..31
    float sx0 = 0.f, sy0 = 0.f, sx1 = 0.f, sy1 = 0.f;
    int i = lo + slot;
    for (; i + 32 < hi; i += 64) {
        unsigned u0 = ((const unsigned*)x)[(size_t)i * 64 + lane];
        unsigned u1 = ((const unsigned*)x)[(size_t)(i + 32) * 64 + lane];
        sx0 += __uint_as_float(u0 << 16);
        sy0 += __uint_as_float(u0 & 0xffff0000u);
        sx1 += __uint_as_float(u1 << 16);
        sy1 += __uint_as_float(u1 & 0xffff0000u);
    }
    if (i < hi) {
        unsigned u0 = ((const unsigned*)x)[(size_t)i * 64 + lane];
        sx0 += __uint_as_float(u0 << 16);
        sy0 += __uint_as_float(u0 & 0xffff0000u);
    }
    __shared__ float2 red[4][64];
    red[wv][lane] = make_float2(sx0 + sx1, sy0 + sy1);
    __syncthreads();
    if (wv == 0) {
        float2 a = red[0][lane], b = red[1][lane], c = red[2][lane], d = red[3][lane];
        float* pp = part + ((size_t)(g * PS + s)) * CH;
        pp[2 * lane] = a.x + b.x + c.x + d.x;
        pp[2 * lane + 1] = a.y + b.y + c.y + d.y;
    }
}

__global__ __launch_bounds__(128) void k_pool2(const float* __restrict__ part,
                                               const int* __restrict__ batchv,
                                               float* __restrict__ outp, int n) {
    int g = blockIdx.x, t = threadIdx.x;
    int lo = lower_bound_dev(batchv, n, g);
    int hi = lower_bound_dev(batchv, n, g + 1);
    float v = 0.f;
#pragma unroll
    for (int s = 0; s < PS; ++s) v += part[((size_t)(g * PS + s)) * CH + t];
    int cnt = hi - lo; if (cnt < 1) cnt = 1;
    outp[(size_t)g * CH + t] = v / (float)cnt;
}

// ---- orchestration ---------------------------------------------------------

extern "C" void kernel_launch(void* const* d_in, const int* in_sizes, int n_in,
                              void* d_out, int out_size, void* d_ws, size_t ws_size,
                              hipStream_t stream) {
    const float* u   = (const float*)d_in[0];
    const float* W1  = (const float*)d_in[1];
    const float* as1 = (const float*)d_in[2];
    const float* ad1 = (const float*)d_in[3];
    const float* b1  = (const float*)d_in[4];
    const float* W2  = (const float*)d_in[5];
    const float* as2 = (const float*)d_in[6];
    const float* ad2 = (const float*)d_in[7];
    const float* b2  = (const float*)d_in[8];
    const int* ei    = (const int*)d_in[9];
    const int* batchv= (const int*)d_in[10];

    const int N = in_sizes[0] / CH;
    const int E = in_sizes[9] / 2;
    const int M = E + N;
    const int NP = (N + PSIZE - 1) >> PSHIFT;
    const int G = out_size / CH;

    char* p = (char*)d_ws;
    auto alloc = [&](size_t bytes) {
        char* r = p;
        p += (bytes + 255) & ~(size_t)255;
        return r;
    };
    int*   pfill  = (int*)alloc((size_t)NP * 4);
    size_t zbytes = (size_t)(p - (char*)d_ws);      // zero pfill
    int*   rowptr = (int*)alloc((size_t)(N + 1) * 4);
    int*   csr    = (int*)alloc((size_t)M * 4);
    float* asv    = (float*)alloc((size_t)N * 4);
    float* adv    = (float*)alloc((size_t)N * 4);
    float* ppart  = (float*)alloc((size_t)G * PS * CH * 4);
    __hip_bfloat16* hbuf = (__hip_bfloat16*)alloc((size_t)N * CH * 2);
    // staged aliases [wedge | x2]: staged is fully consumed by k_fat's build
    // half before agg1 writes x2/wedge. hbuf is separate (written by k_fat's
    // gemm half concurrently with build reading staged).
    size_t wbytes = ((size_t)M * 4 + 255) & ~(size_t)255;
    size_t xbytes = (size_t)N * CH * 2;
    size_t sbytes = (size_t)NP * PCAP * 8;
    size_t blob   = wbytes + xbytes > sbytes ? wbytes + xbytes : sbytes;
    char*  bb     = alloc(blob);
    unsigned long long* staged = (unsigned long long*)bb;
    float* wedge  = (float*)bb;                      // fallback path only
    __hip_bfloat16* x2 = (__hip_bfloat16*)(bb + wbytes);

    hipMemsetAsync(d_ws, 0, zbytes, stream);

    const int gblocks = (N + 127) / 128;

    k_part<<<(E + CHUNK - 1) / CHUNK, 256, 0, stream>>>(ei, pfill, staged, E, NP);
    // build (NP blocks) || gemm layer 1 (gblocks)
    k_fat<<<NP + gblocks, 256, 0, stream>>>(staged, pfill, rowptr, csr, N, E, NP,
                                            u, W1, as1, ad1, hbuf, asv, adv);

    k_fused_agg<<<(N * 64 + 255) / 256, 256, 0, stream>>>(rowptr, csr, asv, adv, wedge, hbuf, b1, x2, N);

    // layer 2 (bf16 input)
    k_gemm3<__hip_bfloat16><<<gblocks, 256, 0, stream>>>(x2, W2, as2, ad2, hbuf, asv, adv, N);
    k_fused_agg<<<(N * 64 + 255) / 256, 256, 0, stream>>>(rowptr, csr, asv, adv, wedge, hbuf, b2, x2, N);

    k_pool1<<<G * PS, 256, 0, stream>>>(x2, batchv, ppart, N);
    k_pool2<<<G, 128, 0, stream>>>(ppart, batchv, (float*)d_out, N);
}

// Round 12
// 201.218 us; speedup vs baseline: 4.0051x; 1.0342x over previous
//
#include <hip/hip_runtime.h>
#include <hip/hip_bf16.h>
#include <math.h>

#define CH 128
#define PSHIFT 8              // 256 nodes per partition
#define PSIZE (1 << PSHIFT)
#define CHUNK 2048            // edges per block in k_part
#define EPT 8                 // edges per thread (256 * 8 = 2048)
#define MAXP 256              // max partitions
#define PCAP 12288            // staging capacity per partition
#define PS 8                  // pool slices per graph

typedef __attribute__((ext_vector_type(8))) short short8;
typedef __attribute__((ext_vector_type(4))) float f32x4;

__device__ __forceinline__ float seluf(float x) {
    const float scale = 1.0507009873554804934193349852946f;
    const float alpha = 1.6732632423543772848170429916717f;
    return x > 0.0f ? scale * x : scale * alpha * (__expf(x) - 1.0f);
}

__device__ __forceinline__ float lrelu(float x) {
    return x > 0.0f ? x : 0.2f * x;
}

__device__ __forceinline__ short bfc(float f) {
    union { __hip_bfloat16 b; short s; } u;
    u.b = __float2bfloat16(f);
    return u.s;
}

__device__ __forceinline__ unsigned pk(float lo, float hi) {
    return ((unsigned)(unsigned short)bfc(hi) << 16) | (unsigned short)bfc(lo);
}

// ---- CSR build pass A ------------------------------------------------------

__global__ __launch_bounds__(256) void k_part(const int* __restrict__ ei,
                                              int* __restrict__ pfill,
                                              unsigned long long* __restrict__ staged,
                                              int E, int NP) {
    __shared__ int hist[MAXP];
    __shared__ int base[MAXP];
    const int tid = threadIdx.x;
    const int j0 = blockIdx.x * CHUNK;
    for (int i = tid; i < NP; i += 256) hist[i] = 0;
    __syncthreads();
    int part[EPT], rank[EPT];
    unsigned long long rec[EPT];
#pragma unroll
    for (int e = 0; e < EPT; ++e) {
        int j = j0 + e * 256 + tid;
        part[e] = -1;
        if (j < E) {
            int s = ei[j], d = ei[E + j];
            part[e] = d >> PSHIFT;
            rec[e] = ((unsigned long long)(unsigned)d << 32) | (unsigned)s;
            rank[e] = atomicAdd(&hist[part[e]], 1);
        }
    }
    __syncthreads();
    for (int i = tid; i < NP; i += 256)
        base[i] = hist[i] ? atomicAdd(&pfill[i], hist[i]) : 0;
    __syncthreads();
#pragma unroll
    for (int e = 0; e < EPT; ++e)
        if (part[e] >= 0)
            staged[(size_t)part[e] * PCAP + base[part[e]] + rank[e]] = rec[e];
}

// ---- fat kernel: CSR build pass B (blocks < NP) || GEMM layer 1 (rest) -----

__global__ __launch_bounds__(256) void k_fat(
    const unsigned long long* __restrict__ staged, const int* __restrict__ pfill,
    int* __restrict__ rowptr, int* __restrict__ csr, int n, int E, int NP,
    const float* __restrict__ x, const float* __restrict__ W,
    const float* __restrict__ a_s, const float* __restrict__ a_d,
    __hip_bfloat16* __restrict__ hb, float* __restrict__ as_o,
    float* __restrict__ ad_o) {
    __shared__ __align__(16) char sm[32768];
    const int tid = threadIdx.x;

    if ((int)blockIdx.x < NP) {
        // ---------------- build path ----------------
        int* lcnt = (int*)sm;            // [256]
        int* lrow = lcnt + PSIZE;        // [256]
        int* sc   = lrow + PSIZE;        // [256]
        int* psc  = sc + PSIZE;          // [256]
        const int p = blockIdx.x;
        const int d0 = p << PSHIFT;
        psc[tid] = (tid < NP) ? pfill[tid] : 0;
        lcnt[tid] = 0;
        __syncthreads();
        for (int off = 1; off < 256; off <<= 1) {
            int v = (tid >= off) ? psc[tid - off] : 0;
            __syncthreads();
            psc[tid] += v;
            __syncthreads();
        }
        const int pbase = psc[p] - pfill[p];   // exclusive prefix of edge counts
        const size_t rbeg = (size_t)p * PCAP;
        const size_t rend = rbeg + pfill[p];
        const int rb = pbase + d0;
        for (size_t r = rbeg + tid; r < rend; r += 256)
            atomicAdd(&lcnt[(int)(staged[r] >> 32) - d0], 1);
        __syncthreads();
        int myv = (d0 + tid < n) ? lcnt[tid] + 1 : 0;
        sc[tid] = myv;
        __syncthreads();
        for (int off = 1; off < 256; off <<= 1) {
            int v = (tid >= off) ? sc[tid - off] : 0;
            __syncthreads();
            sc[tid] += v;
            __syncthreads();
        }
        if (d0 + tid < n) {
            int rp = rb + sc[tid] - myv;
            lrow[tid] = rp;
            rowptr[d0 + tid] = rp;
            csr[rp] = d0 + tid;              // self loop
            lcnt[tid] = 0;                   // reuse as fill counter
        }
        if (p == 0 && tid == 0) rowptr[n] = E + n;
        __syncthreads();
        for (size_t r = rbeg + tid; r < rend; r += 256) {
            unsigned long long v = staged[r];
            int d = (int)(v >> 32), s = (int)(v & 0xffffffffu);
            int pos = lrow[d - d0] + 1 + atomicAdd(&lcnt[d - d0], 1);
            csr[pos] = s;
        }
        return;
    }

    // ---------------- gemm path (layer 1, fp32 input) ----------------
    short* WB = (short*)sm;                  // 16384 bf16 = 32 KB
    for (int i = tid; i < CH * CH; i += 256) {
        int k = i >> 7, c = i & 127;
        int kb = k >> 5, kk = k & 31;
        int t = c >> 4;
        int ln = (c & 15) | ((kk >> 3) << 4);
        int j = kk & 7;
        WB[(((kb << 3) + t) << 9) + (ln << 3) + j] = bfc(W[i]);
    }
    __syncthreads();
    const int bid = blockIdx.x - NP;
    const int lane = tid & 63;
    const int wid = tid >> 6;
    const int l15 = lane & 15;
    const int lhi = lane >> 4;
    float asl[8], adl[8];
#pragma unroll
    for (int t = 0; t < 8; ++t) {
        asl[t] = a_s[t * 16 + l15];
        adl[t] = a_d[t * 16 + l15];
    }
#pragma unroll
    for (int s = 0; s < 2; ++s) {
        int r0 = bid * 128 + s * 64 + wid * 16;
        if (r0 >= n) break;
        int ar = r0 + l15; if (ar >= n) ar = n - 1;
        const float* xr = x + (size_t)ar * CH + lhi * 8;
        f32x4 acc[8];
#pragma unroll
        for (int t = 0; t < 8; ++t) acc[t] = (f32x4){0.f, 0.f, 0.f, 0.f};
#pragma unroll
        for (int kb = 0; kb < 4; ++kb) {
            float4 xa = *(const float4*)(xr + kb * 32);
            float4 xb = *(const float4*)(xr + kb * 32 + 4);
            short8 af;
            af[0] = bfc(xa.x); af[1] = bfc(xa.y); af[2] = bfc(xa.z); af[3] = bfc(xa.w);
            af[4] = bfc(xb.x); af[5] = bfc(xb.y); af[6] = bfc(xb.z); af[7] = bfc(xb.w);
#pragma unroll
            for (int t = 0; t < 8; ++t) {
                short8 bv = ((const short8*)WB)[(((kb << 3) + t) << 6) | lane];
                acc[t] = __builtin_amdgcn_mfma_f32_16x16x32_bf16(af, bv, acc[t], 0, 0, 0);
            }
        }
        float pa[4] = {0.f, 0.f, 0.f, 0.f}, pd[4] = {0.f, 0.f, 0.f, 0.f};
#pragma unroll
        for (int t = 0; t < 8; ++t) {
#pragma unroll
            for (int q = 0; q < 4; ++q) {
                int row = r0 + lhi * 4 + q;
                if (row < n)
                    hb[(size_t)row * CH + t * 16 + l15] = __float2bfloat16(acc[t][q]);
                pa[q] += acc[t][q] * asl[t];
                pd[q] += acc[t][q] * adl[t];
            }
        }
#pragma unroll
        for (int q = 0; q < 4; ++q) {
#pragma unroll
            for (int o = 1; o < 16; o <<= 1) {
                pa[q] += __shfl_xor(pa[q], o);
                pd[q] += __shfl_xor(pd[q], o);
            }
        }
        if (l15 == 0) {
#pragma unroll
            for (int q = 0; q < 4; ++q) {
                int row = r0 + lhi * 4 + q;
                if (row < n) { as_o[row] = pa[q]; ad_o[row] = pd[q]; }
            }
        }
    }
}

// ---- GEMM v3 (standalone, layer 2 bf16 input) ------------------------------

template <typename T>
__global__ __launch_bounds__(256) void k_gemm3(
    const T* __restrict__ x, const float* __restrict__ W,
    const float* __restrict__ a_s, const float* __restrict__ a_d,
    __hip_bfloat16* __restrict__ hb, float* __restrict__ as_o,
    float* __restrict__ ad_o, int n) {
    __shared__ short WB[4 * 8 * 64 * 8];   // 32 KB
    const int tid = threadIdx.x;
    for (int i = tid; i < CH * CH; i += 256) {
        int k = i >> 7, c = i & 127;
        int kb = k >> 5, kk = k & 31;
        int t = c >> 4;
        int ln = (c & 15) | ((kk >> 3) << 4);
        int j = kk & 7;
        WB[(((kb << 3) + t) << 9) + (ln << 3) + j] = bfc(W[i]);
    }
    __syncthreads();
    const int lane = tid & 63;
    const int wid = tid >> 6;
    const int l15 = lane & 15;
    const int lhi = lane >> 4;
    float asl[8], adl[8];
#pragma unroll
    for (int t = 0; t < 8; ++t) {
        asl[t] = a_s[t * 16 + l15];
        adl[t] = a_d[t * 16 + l15];
    }
#pragma unroll
    for (int s = 0; s < 2; ++s) {
        int r0 = blockIdx.x * 128 + s * 64 + wid * 16;
        if (r0 >= n) break;
        int ar = r0 + l15; if (ar >= n) ar = n - 1;
        const T* xr = x + (size_t)ar * CH + lhi * 8;
        f32x4 acc[8];
#pragma unroll
        for (int t = 0; t < 8; ++t) acc[t] = (f32x4){0.f, 0.f, 0.f, 0.f};
#pragma unroll
        for (int kb = 0; kb < 4; ++kb) {
            short8 af;
            if constexpr (sizeof(T) == 4) {
                float4 xa = *(const float4*)(xr + kb * 32);
                float4 xb = *(const float4*)(xr + kb * 32 + 4);
                af[0] = bfc(xa.x); af[1] = bfc(xa.y); af[2] = bfc(xa.z); af[3] = bfc(xa.w);
                af[4] = bfc(xb.x); af[5] = bfc(xb.y); af[6] = bfc(xb.z); af[7] = bfc(xb.w);
            } else {
                af = *(const short8*)(xr + kb * 32);
            }
#pragma unroll
            for (int t = 0; t < 8; ++t) {
                short8 bv = ((const short8*)WB)[(((kb << 3) + t) << 6) | lane];
                acc[t] = __builtin_amdgcn_mfma_f32_16x16x32_bf16(af, bv, acc[t], 0, 0, 0);
            }
        }
        float pa[4] = {0.f, 0.f, 0.f, 0.f}, pd[4] = {0.f, 0.f, 0.f, 0.f};
#pragma unroll
        for (int t = 0; t < 8; ++t) {
#pragma unroll
            for (int q = 0; q < 4; ++q) {
                int row = r0 + lhi * 4 + q;
                if (row < n)
                    hb[(size_t)row * CH + t * 16 + l15] = __float2bfloat16(acc[t][q]);
                pa[q] += acc[t][q] * asl[t];
                pd[q] += acc[t][q] * adl[t];
            }
        }
#pragma unroll
        for (int q = 0; q < 4; ++q) {
#pragma unroll
            for (int o = 1; o < 16; o <<= 1) {
                pa[q] += __shfl_xor(pa[q], o);
                pd[q] += __shfl_xor(pd[q], o);
            }
        }
        if (l15 == 0) {
#pragma unroll
            for (int q = 0; q < 4; ++q) {
                int row = r0 + lhi * 4 + q;
                if (row < n) { as_o[row] = pa[q]; ad_o[row] = pd[q]; }
            }
        }
    }
}

// ---- fused softmax + aggregation: one wave per node, bf16 out --------------
// Phase C: 8 edge-slots/iter, 2 independent uint4 gathers in flight per lane.
// Invalid slots carry w=0 (lanes >= deg), so no bounds checks needed.

__global__ __launch_bounds__(256) void k_fused_agg(
    const int* __restrict__ rowptr, const int* __restrict__ csr,
    const float* __restrict__ as_v, const float* __restrict__ ad_v,
    float* __restrict__ wedge, const __hip_bfloat16* __restrict__ hb,
    const float* __restrict__ bias, __hip_bfloat16* __restrict__ out, int n) {
    int gw = (int)((blockIdx.x * (size_t)blockDim.x + threadIdx.x) >> 6);
    int lane = threadIdx.x & 63;
    if (gw >= n) return;
    int beg = rowptr[gw], end = rowptr[gw + 1];
    int deg = end - beg;
    float adi = ad_v[gw];

    const int quarter = lane >> 4;     // edge sub-slot 0..3
    const int c8 = lane & 15;          // 8-channel block
    float acc[8];
#pragma unroll
    for (int k = 0; k < 8; ++k) acc[k] = 0.f;
    float inv;

    if (deg <= 64) {
        bool valid = lane < deg;
        int src = valid ? csr[beg + lane] : 0;
        float e = valid ? lrelu(as_v[src] + adi) : -1e30f;
        float m = e;
#pragma unroll
        for (int o = 32; o > 0; o >>= 1) m = fmaxf(m, __shfl_xor(m, o));
        float w = valid ? __expf(e - m) : 0.f;
        float s = w;
#pragma unroll
        for (int o = 32; o > 0; o >>= 1) s += __shfl_xor(s, o);
        inv = 1.0f / s;
        // 8 slots per iteration; slots >= deg have w=0 and src=0 (harmless).
        for (int b = 0; b < deg; b += 8) {
            int i0 = b + quarter;          // <= 59+3 < 64
            int i1 = b + 4 + quarter;      // <= 63
            float w0 = __shfl(w, i0);
            int s0 = __shfl(src, i0);
            float w1 = (i1 < 64) ? __shfl(w, i1) : 0.f;
            int s1 = (i1 < 64) ? __shfl(src, i1) : 0;
            uint4 hv0 = ((const uint4*)hb)[(size_t)s0 * 16 + c8];
            uint4 hv1 = ((const uint4*)hb)[(size_t)s1 * 16 + c8];
            acc[0] += w0 * __uint_as_float(hv0.x << 16);
            acc[1] += w0 * __uint_as_float(hv0.x & 0xffff0000u);
            acc[2] += w0 * __uint_as_float(hv0.y << 16);
            acc[3] += w0 * __uint_as_float(hv0.y & 0xffff0000u);
            acc[4] += w0 * __uint_as_float(hv0.z << 16);
            acc[5] += w0 * __uint_as_float(hv0.z & 0xffff0000u);
            acc[6] += w0 * __uint_as_float(hv0.w << 16);
            acc[7] += w0 * __uint_as_float(hv0.w & 0xffff0000u);
            acc[0] += w1 * __uint_as_float(hv1.x << 16);
            acc[1] += w1 * __uint_as_float(hv1.x & 0xffff0000u);
            acc[2] += w1 * __uint_as_float(hv1.y << 16);
            acc[3] += w1 * __uint_as_float(hv1.y & 0xffff0000u);
            acc[4] += w1 * __uint_as_float(hv1.z << 16);
            acc[5] += w1 * __uint_as_float(hv1.z & 0xffff0000u);
            acc[6] += w1 * __uint_as_float(hv1.w << 16);
            acc[7] += w1 * __uint_as_float(hv1.w & 0xffff0000u);
        }
    } else {
        float m = -1e30f;
        for (int p = beg + lane; p < end; p += 64) {
            float e = lrelu(as_v[csr[p]] + adi);
            wedge[p] = e;
            m = fmaxf(m, e);
        }
#pragma unroll
        for (int o = 32; o > 0; o >>= 1) m = fmaxf(m, __shfl_xor(m, o));
        float s = 0.f;
        for (int p = beg + lane; p < end; p += 64) {
            float wv = __expf(wedge[p] - m);
            wedge[p] = wv;
            s += wv;
        }
#pragma unroll
        for (int o = 32; o > 0; o >>= 1) s += __shfl_xor(s, o);
        inv = 1.0f / s;
        for (int p = beg; p < end; p += 8) {
            int p0 = p + quarter, p1 = p + 4 + quarter;
            float w0 = 0.f, w1 = 0.f;
            int s0 = 0, s1 = 0;
            if (p0 < end) { w0 = wedge[p0]; s0 = csr[p0]; }
            if (p1 < end) { w1 = wedge[p1]; s1 = csr[p1]; }
            uint4 hv0 = ((const uint4*)hb)[(size_t)s0 * 16 + c8];
            uint4 hv1 = ((const uint4*)hb)[(size_t)s1 * 16 + c8];
            acc[0] += w0 * __uint_as_float(hv0.x << 16);
            acc[1] += w0 * __uint_as_float(hv0.x & 0xffff0000u);
            acc[2] += w0 * __uint_as_float(hv0.y << 16);
            acc[3] += w0 * __uint_as_float(hv0.y & 0xffff0000u);
            acc[4] += w0 * __uint_as_float(hv0.z << 16);
            acc[5] += w0 * __uint_as_float(hv0.z & 0xffff0000u);
            acc[6] += w0 * __uint_as_float(hv0.w << 16);
            acc[7] += w0 * __uint_as_float(hv0.w & 0xffff0000u);
            acc[0] += w1 * __uint_as_float(hv1.x << 16);
            acc[1] += w1 * __uint_as_float(hv1.x & 0xffff0000u);
            acc[2] += w1 * __uint_as_float(hv1.y << 16);
            acc[3] += w1 * __uint_as_float(hv1.y & 0xffff0000u);
            acc[4] += w1 * __uint_as_float(hv1.z << 16);
            acc[5] += w1 * __uint_as_float(hv1.z & 0xffff0000u);
            acc[6] += w1 * __uint_as_float(hv1.w << 16);
            acc[7] += w1 * __uint_as_float(hv1.w & 0xffff0000u);
        }
    }
#pragma unroll
    for (int k = 0; k < 8; ++k) {
        acc[k] += __shfl_xor(acc[k], 16);
        acc[k] += __shfl_xor(acc[k], 32);
    }
    if (quarter == 0) {
        const float4 bv0 = ((const float4*)bias)[c8 * 2];
        const float4 bv1 = ((const float4*)bias)[c8 * 2 + 1];
        float o0 = seluf(acc[0] * inv + bv0.x);
        float o1 = seluf(acc[1] * inv + bv0.y);
        float o2 = seluf(acc[2] * inv + bv0.z);
        float o3 = seluf(acc[3] * inv + bv0.w);
        float o4 = seluf(acc[4] * inv + bv1.x);
        float o5 = seluf(acc[5] * inv + bv1.y);
        float o6 = seluf(acc[6] * inv + bv1.z);
        float o7 = seluf(acc[7] * inv + bv1.w);
        uint4 ov;
        ov.x = pk(o0, o1);
        ov.y = pk(o2, o3);
        ov.z = pk(o4, o5);
        ov.w = pk(o6, o7);
        ((uint4*)out)[(size_t)gw * 16 + c8] = ov;
    }
}

// ---- global mean pool: two-stage deterministic reduction -------------------

__device__ int lower_bound_dev(const int* a, int n, int key) {
    int lo = 0, hi = n;
    while (lo < hi) {
        int mid = (lo + hi) >> 1;
        if (a[mid] < key) lo = mid + 1; else hi = mid;
    }
    return lo;
}

__global__ __launch_bounds__(256) void k_pool1(const __hip_bfloat16* __restrict__ x,
                                               const int* __restrict__ batchv,
                                               float* __restrict__ part, int n) {
    int g = blockIdx.x >> 3, s = blockIdx.x & (PS - 1);
    int lo = lower_bound_dev(batchv, n, g);
    int hi = lower_bound_dev(batchv, n, g + 1);
    int lane = threadIdx.x & 63, wv = threadIdx.x >> 6;
    int slot = s * 4 + wv;             // 0..31
    float sx0 = 0.f, sy0 = 0.f, sx1 = 0.f, sy1 = 0.f;
    int i = lo + slot;
    for (; i + 32 < hi; i += 64) {
        unsigned u0 = ((const unsigned*)x)[(size_t)i * 64 + lane];
        unsigned u1 = ((const unsigned*)x)[(size_t)(i + 32) * 64 + lane];
        sx0 += __uint_as_float(u0 << 16);
        sy0 += __uint_as_float(u0 & 0xffff0000u);
        sx1 += __uint_as_float(u1 << 16);
        sy1 += __uint_as_float(u1 & 0xffff0000u);
    }
    if (i < hi) {
        unsigned u0 = ((const unsigned*)x)[(size_t)i * 64 + lane];
        sx0 += __uint_as_float(u0 << 16);
        sy0 += __uint_as_float(u0 & 0xffff0000u);
    }
    __shared__ float2 red[4][64];
    red[wv][lane] = make_float2(sx0 + sx1, sy0 + sy1);
    __syncthreads();
    if (wv == 0) {
        float2 a = red[0][lane], b = red[1][lane], c = red[2][lane], d = red[3][lane];
        float* pp = part + ((size_t)(g * PS + s)) * CH;
        pp[2 * lane] = a.x + b.x + c.x + d.x;
        pp[2 * lane + 1] = a.y + b.y + c.y + d.y;
    }
}

__global__ __launch_bounds__(128) void k_pool2(const float* __restrict__ part,
                                               const int* __restrict__ batchv,
                                               float* __restrict__ outp, int n) {
    int g = blockIdx.x, t = threadIdx.x;
    int lo = lower_bound_dev(batchv, n, g);
    int hi = lower_bound_dev(batchv, n, g + 1);
    float v = 0.f;
#pragma unroll
    for (int s = 0; s < PS; ++s) v += part[((size_t)(g * PS + s)) * CH + t];
    int cnt = hi - lo; if (cnt < 1) cnt = 1;
    outp[(size_t)g * CH + t] = v / (float)cnt;
}

// ---- orchestration ---------------------------------------------------------

extern "C" void kernel_launch(void* const* d_in, const int* in_sizes, int n_in,
                              void* d_out, int out_size, void* d_ws, size_t ws_size,
                              hipStream_t stream) {
    const float* u   = (const float*)d_in[0];
    const float* W1  = (const float*)d_in[1];
    const float* as1 = (const float*)d_in[2];
    const float* ad1 = (const float*)d_in[3];
    const float* b1  = (const float*)d_in[4];
    const float* W2  = (const float*)d_in[5];
    const float* as2 = (const float*)d_in[6];
    const float* ad2 = (const float*)d_in[7];
    const float* b2  = (const float*)d_in[8];
    const int* ei    = (const int*)d_in[9];
    const int* batchv= (const int*)d_in[10];

    const int N = in_sizes[0] / CH;
    const int E = in_sizes[9] / 2;
    const int M = E + N;
    const int NP = (N + PSIZE - 1) >> PSHIFT;
    const int G = out_size / CH;

    char* p = (char*)d_ws;
    auto alloc = [&](size_t bytes) {
        char* r = p;
        p += (bytes + 255) & ~(size_t)255;
        return r;
    };
    int*   pfill  = (int*)alloc((size_t)NP * 4);
    size_t zbytes = (size_t)(p - (char*)d_ws);      // zero pfill
    int*   rowptr = (int*)alloc((size_t)(N + 1) * 4);
    int*   csr    = (int*)alloc((size_t)M * 4);
    float* asv    = (float*)alloc((size_t)N * 4);
    float* adv    = (float*)alloc((size_t)N * 4);
    float* ppart  = (float*)alloc((size_t)G * PS * CH * 4);
    __hip_bfloat16* hbuf = (__hip_bfloat16*)alloc((size_t)N * CH * 2);
    // staged aliases [wedge | x2]: staged is fully consumed by k_fat's build
    // half before agg1 writes x2/wedge.
    size_t wbytes = ((size_t)M * 4 + 255) & ~(size_t)255;
    size_t xbytes = (size_t)N * CH * 2;
    size_t sbytes = (size_t)NP * PCAP * 8;
    size_t blob   = wbytes + xbytes > sbytes ? wbytes + xbytes : sbytes;
    char*  bb     = alloc(blob);
    unsigned long long* staged = (unsigned long long*)bb;
    float* wedge  = (float*)bb;                      // fallback path only
    __hip_bfloat16* x2 = (__hip_bfloat16*)(bb + wbytes);

    hipMemsetAsync(d_ws, 0, zbytes, stream);

    const int gblocks = (N + 127) / 128;

    k_part<<<(E + CHUNK - 1) / CHUNK, 256, 0, stream>>>(ei, pfill, staged, E, NP);
    // build (NP blocks) || gemm layer 1 (gblocks)
    k_fat<<<NP + gblocks, 256, 0, stream>>>(staged, pfill, rowptr, csr, N, E, NP,
                                            u, W1, as1, ad1, hbuf, asv, adv);

    k_fused_agg<<<(N * 64 + 255) / 256, 256, 0, stream>>>(rowptr, csr, asv, adv, wedge, hbuf, b1, x2, N);

    // layer 2 (bf16 input)
    k_gemm3<__hip_bfloat16><<<gblocks, 256, 0, stream>>>(x2, W2, as2, ad2, hbuf, asv, adv, N);
    k_fused_agg<<<(N * 64 + 255) / 256, 256, 0, stream>>>(rowptr, csr, asv, adv, wedge, hbuf, b2, x2, N);

    k_pool1<<<G * PS, 256, 0, stream>>>(x2, batchv, ppart, N);
    k_pool2<<<G, 128, 0, stream>>>(ppart, batchv, (float*)d_out, N);
}

// Round 13
// 190.566 us; speedup vs baseline: 4.2290x; 1.0559x over previous
//
#include <hip/hip_runtime.h>
#include <hip/hip_bf16.h>
#include <math.h>

#define CH 128
#define PSHIFT 8              // 256 nodes per partition
#define PSIZE (1 << PSHIFT)
#define CHUNK 4096            // edges per block in k_part
#define EPT 16                // edges per thread (256 * 16 = 4096)
#define MAXP 256              // max partitions
#define PCAP 12288            // staging capacity per partition
#define PS 8

typedef __attribute__((ext_vector_type(8))) short short8;
typedef __attribute__((ext_vector_type(4))) float f32x4;

__device__ __forceinline__ float seluf(float x) {
    const float scale = 1.0507009873554804934193349852946f;
    const float alpha = 1.6732632423543772848170429916717f;
    return x > 0.0f ? scale * x : scale * alpha * (__expf(x) - 1.0f);
}

__device__ __forceinline__ float lrelu(float x) {
    return x > 0.0f ? x : 0.2f * x;
}

__device__ __forceinline__ short bfc(float f) {
    union { __hip_bfloat16 b; short s; } u;
    u.b = __float2bfloat16(f);
    return u.s;
}

__device__ __forceinline__ unsigned pk(float lo, float hi) {
    return ((unsigned)(unsigned short)bfc(hi) << 16) | (unsigned short)bfc(lo);
}

// ---- CSR build pass A: 4B records ((dst-d0)<<24 | src), src < 2^24 ---------

__global__ __launch_bounds__(256) void k_part(const int* __restrict__ ei,
                                              int* __restrict__ pfill,
                                              unsigned* __restrict__ staged,
                                              int E, int NP) {
    __shared__ int hist[MAXP];
    __shared__ int base[MAXP];
    const int tid = threadIdx.x;
    const int j0 = blockIdx.x * CHUNK;
    for (int i = tid; i < NP; i += 256) hist[i] = 0;
    __syncthreads();
    int part[EPT], rank[EPT];
    unsigned rec[EPT];
#pragma unroll
    for (int e = 0; e < EPT; ++e) {
        int j = j0 + e * 256 + tid;
        part[e] = -1;
        if (j < E) {
            int s = ei[j], d = ei[E + j];
            part[e] = d >> PSHIFT;
            rec[e] = ((unsigned)(d & (PSIZE - 1)) << 24) | (unsigned)s;
            rank[e] = atomicAdd(&hist[part[e]], 1);
        }
    }
    __syncthreads();
    for (int i = tid; i < NP; i += 256)
        base[i] = hist[i] ? atomicAdd(&pfill[i], hist[i]) : 0;
    __syncthreads();
#pragma unroll
    for (int e = 0; e < EPT; ++e)
        if (part[e] >= 0)
            staged[(size_t)part[e] * PCAP + base[part[e]] + rank[e]] = rec[e];
}

// ---- fat kernel: CSR build pass B (blocks < NP) || GEMM layer 1 (rest) -----

__global__ __launch_bounds__(256) void k_fat(
    const unsigned* __restrict__ staged, const int* __restrict__ pfill,
    int* __restrict__ rowptr, int* __restrict__ csr, int n, int E, int NP,
    const float* __restrict__ x, const float* __restrict__ W,
    const float* __restrict__ a_s, const float* __restrict__ a_d,
    __hip_bfloat16* __restrict__ hb, float* __restrict__ as_o,
    float* __restrict__ ad_o) {
    __shared__ __align__(16) char sm[32768];
    const int tid = threadIdx.x;

    if ((int)blockIdx.x < NP) {
        // ---------------- build path ----------------
        int* lcnt = (int*)sm;            // [256]
        int* lrow = lcnt + PSIZE;        // [256]
        int* sc   = lrow + PSIZE;        // [256]
        int* psc  = sc + PSIZE;          // [256]
        const int p = blockIdx.x;
        const int d0 = p << PSHIFT;
        psc[tid] = (tid < NP) ? pfill[tid] : 0;
        lcnt[tid] = 0;
        __syncthreads();
        for (int off = 1; off < 256; off <<= 1) {
            int v = (tid >= off) ? psc[tid - off] : 0;
            __syncthreads();
            psc[tid] += v;
            __syncthreads();
        }
        const int pbase = psc[p] - pfill[p];
        const size_t rbeg = (size_t)p * PCAP;
        const size_t rend = rbeg + pfill[p];
        const int rb = pbase + d0;
        for (size_t r = rbeg + tid; r < rend; r += 256)
            atomicAdd(&lcnt[staged[r] >> 24], 1);
        __syncthreads();
        int myv = (d0 + tid < n) ? lcnt[tid] + 1 : 0;
        sc[tid] = myv;
        __syncthreads();
        for (int off = 1; off < 256; off <<= 1) {
            int v = (tid >= off) ? sc[tid - off] : 0;
            __syncthreads();
            sc[tid] += v;
            __syncthreads();
        }
        if (d0 + tid < n) {
            int rp = rb + sc[tid] - myv;
            lrow[tid] = rp;
            rowptr[d0 + tid] = rp;
            csr[rp] = d0 + tid;              // self loop
            lcnt[tid] = 0;                   // reuse as fill counter
        }
        if (p == 0 && tid == 0) rowptr[n] = E + n;
        __syncthreads();
        for (size_t r = rbeg + tid; r < rend; r += 256) {
            unsigned v = staged[r];
            int dd = v >> 24, s = (int)(v & 0xFFFFFFu);
            int pos = lrow[dd] + 1 + atomicAdd(&lcnt[dd], 1);
            csr[pos] = s;
        }
        return;
    }

    // ---------------- gemm path (layer 1, fp32 input) ----------------
    short* WB = (short*)sm;                  // 32 KB
    for (int i = tid; i < CH * CH; i += 256) {
        int k = i >> 7, c = i & 127;
        int kb = k >> 5, kk = k & 31;
        int t = c >> 4;
        int ln = (c & 15) | ((kk >> 3) << 4);
        int j = kk & 7;
        WB[(((kb << 3) + t) << 9) + (ln << 3) + j] = bfc(W[i]);
    }
    __syncthreads();
    const int bid = blockIdx.x - NP;
    const int lane = tid & 63;
    const int wid = tid >> 6;
    const int l15 = lane & 15;
    const int lhi = lane >> 4;
    float asl[8], adl[8];
#pragma unroll
    for (int t = 0; t < 8; ++t) {
        asl[t] = a_s[t * 16 + l15];
        adl[t] = a_d[t * 16 + l15];
    }
#pragma unroll
    for (int s = 0; s < 2; ++s) {
        int r0 = bid * 128 + s * 64 + wid * 16;
        if (r0 >= n) break;
        int ar = r0 + l15; if (ar >= n) ar = n - 1;
        const float* xr = x + (size_t)ar * CH + lhi * 8;
        f32x4 acc[8];
#pragma unroll
        for (int t = 0; t < 8; ++t) acc[t] = (f32x4){0.f, 0.f, 0.f, 0.f};
#pragma unroll
        for (int kb = 0; kb < 4; ++kb) {
            float4 xa = *(const float4*)(xr + kb * 32);
            float4 xb = *(const float4*)(xr + kb * 32 + 4);
            short8 af;
            af[0] = bfc(xa.x); af[1] = bfc(xa.y); af[2] = bfc(xa.z); af[3] = bfc(xa.w);
            af[4] = bfc(xb.x); af[5] = bfc(xb.y); af[6] = bfc(xb.z); af[7] = bfc(xb.w);
#pragma unroll
            for (int t = 0; t < 8; ++t) {
                short8 bv = ((const short8*)WB)[(((kb << 3) + t) << 6) | lane];
                acc[t] = __builtin_amdgcn_mfma_f32_16x16x32_bf16(af, bv, acc[t], 0, 0, 0);
            }
        }
        float pa[4] = {0.f, 0.f, 0.f, 0.f}, pd[4] = {0.f, 0.f, 0.f, 0.f};
#pragma unroll
        for (int t = 0; t < 8; ++t) {
#pragma unroll
            for (int q = 0; q < 4; ++q) {
                int row = r0 + lhi * 4 + q;
                if (row < n)
                    hb[(size_t)row * CH + t * 16 + l15] = __float2bfloat16(acc[t][q]);
                pa[q] += acc[t][q] * asl[t];
                pd[q] += acc[t][q] * adl[t];
            }
        }
#pragma unroll
        for (int q = 0; q < 4; ++q) {
#pragma unroll
            for (int o = 1; o < 16; o <<= 1) {
                pa[q] += __shfl_xor(pa[q], o);
                pd[q] += __shfl_xor(pd[q], o);
            }
        }
        if (l15 == 0) {
#pragma unroll
            for (int q = 0; q < 4; ++q) {
                int row = r0 + lhi * 4 + q;
                if (row < n) { as_o[row] = pa[q]; ad_o[row] = pd[q]; }
            }
        }
    }
}

// ---- GEMM v3 (standalone, layer 2 bf16 input) ------------------------------

template <typename T>
__global__ __launch_bounds__(256) void k_gemm3(
    const T* __restrict__ x, const float* __restrict__ W,
    const float* __restrict__ a_s, const float* __restrict__ a_d,
    __hip_bfloat16* __restrict__ hb, float* __restrict__ as_o,
    float* __restrict__ ad_o, int n) {
    __shared__ short WB[4 * 8 * 64 * 8];   // 32 KB
    const int tid = threadIdx.x;
    for (int i = tid; i < CH * CH; i += 256) {
        int k = i >> 7, c = i & 127;
        int kb = k >> 5, kk = k & 31;
        int t = c >> 4;
        int ln = (c & 15) | ((kk >> 3) << 4);
        int j = kk & 7;
        WB[(((kb << 3) + t) << 9) + (ln << 3) + j] = bfc(W[i]);
    }
    __syncthreads();
    const int lane = tid & 63;
    const int wid = tid >> 6;
    const int l15 = lane & 15;
    const int lhi = lane >> 4;
    float asl[8], adl[8];
#pragma unroll
    for (int t = 0; t < 8; ++t) {
        asl[t] = a_s[t * 16 + l15];
        adl[t] = a_d[t * 16 + l15];
    }
#pragma unroll
    for (int s = 0; s < 2; ++s) {
        int r0 = blockIdx.x * 128 + s * 64 + wid * 16;
        if (r0 >= n) break;
        int ar = r0 + l15; if (ar >= n) ar = n - 1;
        const T* xr = x + (size_t)ar * CH + lhi * 8;
        f32x4 acc[8];
#pragma unroll
        for (int t = 0; t < 8; ++t) acc[t] = (f32x4){0.f, 0.f, 0.f, 0.f};
#pragma unroll
        for (int kb = 0; kb < 4; ++kb) {
            short8 af;
            if constexpr (sizeof(T) == 4) {
                float4 xa = *(const float4*)(xr + kb * 32);
                float4 xb = *(const float4*)(xr + kb * 32 + 4);
                af[0] = bfc(xa.x); af[1] = bfc(xa.y); af[2] = bfc(xa.z); af[3] = bfc(xa.w);
                af[4] = bfc(xb.x); af[5] = bfc(xb.y); af[6] = bfc(xb.z); af[7] = bfc(xb.w);
            } else {
                af = *(const short8*)(xr + kb * 32);
            }
#pragma unroll
            for (int t = 0; t < 8; ++t) {
                short8 bv = ((const short8*)WB)[(((kb << 3) + t) << 6) | lane];
                acc[t] = __builtin_amdgcn_mfma_f32_16x16x32_bf16(af, bv, acc[t], 0, 0, 0);
            }
        }
        float pa[4] = {0.f, 0.f, 0.f, 0.f}, pd[4] = {0.f, 0.f, 0.f, 0.f};
#pragma unroll
        for (int t = 0; t < 8; ++t) {
#pragma unroll
            for (int q = 0; q < 4; ++q) {
                int row = r0 + lhi * 4 + q;
                if (row < n)
                    hb[(size_t)row * CH + t * 16 + l15] = __float2bfloat16(acc[t][q]);
                pa[q] += acc[t][q] * asl[t];
                pd[q] += acc[t][q] * adl[t];
            }
        }
#pragma unroll
        for (int q = 0; q < 4; ++q) {
#pragma unroll
            for (int o = 1; o < 16; o <<= 1) {
                pa[q] += __shfl_xor(pa[q], o);
                pd[q] += __shfl_xor(pd[q], o);
            }
        }
        if (l15 == 0) {
#pragma unroll
            for (int q = 0; q < 4; ++q) {
                int row = r0 + lhi * 4 + q;
                if (row < n) { as_o[row] = pa[q]; ad_o[row] = pd[q]; }
            }
        }
    }
}

// ---- fused softmax + aggregation: one wave per node, bf16 out --------------
// Phase C fast path: 16 edge-slots/iter, 4 uint4 gathers in flight.

__global__ __launch_bounds__(256) void k_fused_agg(
    const int* __restrict__ rowptr, const int* __restrict__ csr,
    const float* __restrict__ as_v, const float* __restrict__ ad_v,
    float* __restrict__ wedge, const __hip_bfloat16* __restrict__ hb,
    const float* __restrict__ bias, __hip_bfloat16* __restrict__ out, int n) {
    int gw = (int)((blockIdx.x * (size_t)blockDim.x + threadIdx.x) >> 6);
    int lane = threadIdx.x & 63;
    if (gw >= n) return;
    int beg = rowptr[gw], end = rowptr[gw + 1];
    int deg = end - beg;
    float adi = ad_v[gw];

    const int quarter = lane >> 4;
    const int c8 = lane & 15;
    float acc[8];
#pragma unroll
    for (int k = 0; k < 8; ++k) acc[k] = 0.f;
    float inv;

    if (deg <= 64) {
        bool valid = lane < deg;
        int src = valid ? csr[beg + lane] : 0;
        float e = valid ? lrelu(as_v[src] + adi) : -1e30f;
        float m = e;
#pragma unroll
        for (int o = 32; o > 0; o >>= 1) m = fmaxf(m, __shfl_xor(m, o));
        float w = valid ? __expf(e - m) : 0.f;
        float s = w;
#pragma unroll
        for (int o = 32; o > 0; o >>= 1) s += __shfl_xor(s, o);
        inv = 1.0f / s;
        // 16 slots/iter; slots >= deg carry w=0, src=0; indices always < 64.
        for (int b = 0; b < deg; b += 16) {
            int i0 = b + quarter, i1 = b + 4 + quarter;
            int i2 = b + 8 + quarter, i3 = b + 12 + quarter;
            float w0 = __shfl(w, i0), w1 = __shfl(w, i1);
            float w2 = __shfl(w, i2), w3 = __shfl(w, i3);
            int s0 = __shfl(src, i0), s1 = __shfl(src, i1);
            int s2 = __shfl(src, i2), s3 = __shfl(src, i3);
            uint4 hv0 = ((const uint4*)hb)[(size_t)s0 * 16 + c8];
            uint4 hv1 = ((const uint4*)hb)[(size_t)s1 * 16 + c8];
            uint4 hv2 = ((const uint4*)hb)[(size_t)s2 * 16 + c8];
            uint4 hv3 = ((const uint4*)hb)[(size_t)s3 * 16 + c8];
            acc[0] += w0 * __uint_as_float(hv0.x << 16);
            acc[1] += w0 * __uint_as_float(hv0.x & 0xffff0000u);
            acc[2] += w0 * __uint_as_float(hv0.y << 16);
            acc[3] += w0 * __uint_as_float(hv0.y & 0xffff0000u);
            acc[4] += w0 * __uint_as_float(hv0.z << 16);
            acc[5] += w0 * __uint_as_float(hv0.z & 0xffff0000u);
            acc[6] += w0 * __uint_as_float(hv0.w << 16);
            acc[7] += w0 * __uint_as_float(hv0.w & 0xffff0000u);
            acc[0] += w1 * __uint_as_float(hv1.x << 16);
            acc[1] += w1 * __uint_as_float(hv1.x & 0xffff0000u);
            acc[2] += w1 * __uint_as_float(hv1.y << 16);
            acc[3] += w1 * __uint_as_float(hv1.y & 0xffff0000u);
            acc[4] += w1 * __uint_as_float(hv1.z << 16);
            acc[5] += w1 * __uint_as_float(hv1.z & 0xffff0000u);
            acc[6] += w1 * __uint_as_float(hv1.w << 16);
            acc[7] += w1 * __uint_as_float(hv1.w & 0xffff0000u);
            acc[0] += w2 * __uint_as_float(hv2.x << 16);
            acc[1] += w2 * __uint_as_float(hv2.x & 0xffff0000u);
            acc[2] += w2 * __uint_as_float(hv2.y << 16);
            acc[3] += w2 * __uint_as_float(hv2.y & 0xffff0000u);
            acc[4] += w2 * __uint_as_float(hv2.z << 16);
            acc[5] += w2 * __uint_as_float(hv2.z & 0xffff0000u);
            acc[6] += w2 * __uint_as_float(hv2.w << 16);
            acc[7] += w2 * __uint_as_float(hv2.w & 0xffff0000u);
            acc[0] += w3 * __uint_as_float(hv3.x << 16);
            acc[1] += w3 * __uint_as_float(hv3.x & 0xffff0000u);
            acc[2] += w3 * __uint_as_float(hv3.y << 16);
            acc[3] += w3 * __uint_as_float(hv3.y & 0xffff0000u);
            acc[4] += w3 * __uint_as_float(hv3.z << 16);
            acc[5] += w3 * __uint_as_float(hv3.z & 0xffff0000u);
            acc[6] += w3 * __uint_as_float(hv3.w << 16);
            acc[7] += w3 * __uint_as_float(hv3.w & 0xffff0000u);
        }
    } else {
        float m = -1e30f;
        for (int p = beg + lane; p < end; p += 64) {
            float e = lrelu(as_v[csr[p]] + adi);
            wedge[p] = e;
            m = fmaxf(m, e);
        }
#pragma unroll
        for (int o = 32; o > 0; o >>= 1) m = fmaxf(m, __shfl_xor(m, o));
        float s = 0.f;
        for (int p = beg + lane; p < end; p += 64) {
            float wv = __expf(wedge[p] - m);
            wedge[p] = wv;
            s += wv;
        }
#pragma unroll
        for (int o = 32; o > 0; o >>= 1) s += __shfl_xor(s, o);
        inv = 1.0f / s;
        for (int p = beg; p < end; p += 8) {
            int p0 = p + quarter, p1 = p + 4 + quarter;
            float w0 = 0.f, w1 = 0.f;
            int s0 = 0, s1 = 0;
            if (p0 < end) { w0 = wedge[p0]; s0 = csr[p0]; }
            if (p1 < end) { w1 = wedge[p1]; s1 = csr[p1]; }
            uint4 hv0 = ((const uint4*)hb)[(size_t)s0 * 16 + c8];
            uint4 hv1 = ((const uint4*)hb)[(size_t)s1 * 16 + c8];
            acc[0] += w0 * __uint_as_float(hv0.x << 16);
            acc[1] += w0 * __uint_as_float(hv0.x & 0xffff0000u);
            acc[2] += w0 * __uint_as_float(hv0.y << 16);
            acc[3] += w0 * __uint_as_float(hv0.y & 0xffff0000u);
            acc[4] += w0 * __uint_as_float(hv0.z << 16);
            acc[5] += w0 * __uint_as_float(hv0.z & 0xffff0000u);
            acc[6] += w0 * __uint_as_float(hv0.w << 16);
            acc[7] += w0 * __uint_as_float(hv0.w & 0xffff0000u);
            acc[0] += w1 * __uint_as_float(hv1.x << 16);
            acc[1] += w1 * __uint_as_float(hv1.x & 0xffff0000u);
            acc[2] += w1 * __uint_as_float(hv1.y << 16);
            acc[3] += w1 * __uint_as_float(hv1.y & 0xffff0000u);
            acc[4] += w1 * __uint_as_float(hv1.z << 16);
            acc[5] += w1 * __uint_as_float(hv1.z & 0xffff0000u);
            acc[6] += w1 * __uint_as_float(hv1.w << 16);
            acc[7] += w1 * __uint_as_float(hv1.w & 0xffff0000u);
        }
    }
#pragma unroll
    for (int k = 0; k < 8; ++k) {
        acc[k] += __shfl_xor(acc[k], 16);
        acc[k] += __shfl_xor(acc[k], 32);
    }
    if (quarter == 0) {
        const float4 bv0 = ((const float4*)bias)[c8 * 2];
        const float4 bv1 = ((const float4*)bias)[c8 * 2 + 1];
        float o0 = seluf(acc[0] * inv + bv0.x);
        float o1 = seluf(acc[1] * inv + bv0.y);
        float o2 = seluf(acc[2] * inv + bv0.z);
        float o3 = seluf(acc[3] * inv + bv0.w);
        float o4 = seluf(acc[4] * inv + bv1.x);
        float o5 = seluf(acc[5] * inv + bv1.y);
        float o6 = seluf(acc[6] * inv + bv1.z);
        float o7 = seluf(acc[7] * inv + bv1.w);
        uint4 ov;
        ov.x = pk(o0, o1);
        ov.y = pk(o2, o3);
        ov.z = pk(o4, o5);
        ov.w = pk(o6, o7);
        ((uint4*)out)[(size_t)gw * 16 + c8] = ov;
    }
}

// ---- global mean pool: single launch, 16 waves per graph -------------------

__device__ int lower_bound_dev(const int* a, int n, int key) {
    int lo = 0, hi = n;
    while (lo < hi) {
        int mid = (lo + hi) >> 1;
        if (a[mid] < key) lo = mid + 1; else hi = mid;
    }
    return lo;
}

__global__ __launch_bounds__(1024) void k_pool(const __hip_bfloat16* __restrict__ x,
                                               const int* __restrict__ batchv,
                                               float* __restrict__ outp, int n) {
    int g = blockIdx.x;
    int lo = lower_bound_dev(batchv, n, g);
    int hi = lower_bound_dev(batchv, n, g + 1);
    int lane = threadIdx.x & 63, wv = threadIdx.x >> 6;   // wv: 0..15
    float sx0 = 0.f, sy0 = 0.f, sx1 = 0.f, sy1 = 0.f;
    int i = lo + wv;
    for (; i + 16 < hi; i += 32) {
        unsigned u0 = ((const unsigned*)x)[(size_t)i * 64 + lane];
        unsigned u1 = ((const unsigned*)x)[(size_t)(i + 16) * 64 + lane];
        sx0 += __uint_as_float(u0 << 16);
        sy0 += __uint_as_float(u0 & 0xffff0000u);
        sx1 += __uint_as_float(u1 << 16);
        sy1 += __uint_as_float(u1 & 0xffff0000u);
    }
    if (i < hi) {
        unsigned u0 = ((const unsigned*)x)[(size_t)i * 64 + lane];
        sx0 += __uint_as_float(u0 << 16);
        sy0 += __uint_as_float(u0 & 0xffff0000u);
    }
    __shared__ float2 red[16][64];
    red[wv][lane] = make_float2(sx0 + sx1, sy0 + sy1);
    __syncthreads();
    if (wv == 0) {
        float ax = 0.f, ay = 0.f;
#pragma unroll
        for (int s = 0; s < 16; ++s) { ax += red[s][lane].x; ay += red[s][lane].y; }
        int cnt = hi - lo; if (cnt < 1) cnt = 1;
        float invc = 1.0f / (float)cnt;
        outp[(size_t)g * CH + 2 * lane] = ax * invc;
        outp[(size_t)g * CH + 2 * lane + 1] = ay * invc;
    }
}

// ---- orchestration ---------------------------------------------------------

extern "C" void kernel_launch(void* const* d_in, const int* in_sizes, int n_in,
                              void* d_out, int out_size, void* d_ws, size_t ws_size,
                              hipStream_t stream) {
    const float* u   = (const float*)d_in[0];
    const float* W1  = (const float*)d_in[1];
    const float* as1 = (const float*)d_in[2];
    const float* ad1 = (const float*)d_in[3];
    const float* b1  = (const float*)d_in[4];
    const float* W2  = (const float*)d_in[5];
    const float* as2 = (const float*)d_in[6];
    const float* ad2 = (const float*)d_in[7];
    const float* b2  = (const float*)d_in[8];
    const int* ei    = (const int*)d_in[9];
    const int* batchv= (const int*)d_in[10];

    const int N = in_sizes[0] / CH;
    const int E = in_sizes[9] / 2;
    const int M = E + N;
    const int NP = (N + PSIZE - 1) >> PSHIFT;
    const int G = out_size / CH;

    char* p = (char*)d_ws;
    auto alloc = [&](size_t bytes) {
        char* r = p;
        p += (bytes + 255) & ~(size_t)255;
        return r;
    };
    int*   pfill  = (int*)alloc((size_t)NP * 4);
    size_t zbytes = (size_t)(p - (char*)d_ws);      // zero pfill
    int*   rowptr = (int*)alloc((size_t)(N + 1) * 4);
    int*   csr    = (int*)alloc((size_t)M * 4);
    float* asv    = (float*)alloc((size_t)N * 4);
    float* adv    = (float*)alloc((size_t)N * 4);
    __hip_bfloat16* hbuf = (__hip_bfloat16*)alloc((size_t)N * CH * 2);
    // staged aliases [wedge | x2]: staged fully consumed by k_fat's build half
    // before agg1 writes x2/wedge.
    size_t wbytes = ((size_t)M * 4 + 255) & ~(size_t)255;
    size_t xbytes = (size_t)N * CH * 2;
    size_t sbytes = (size_t)NP * PCAP * 4;
    size_t blob   = wbytes + xbytes > sbytes ? wbytes + xbytes : sbytes;
    char*  bb     = alloc(blob);
    unsigned* staged = (unsigned*)bb;
    float* wedge  = (float*)bb;                      // fallback path only
    __hip_bfloat16* x2 = (__hip_bfloat16*)(bb + wbytes);

    hipMemsetAsync(d_ws, 0, zbytes, stream);

    const int gblocks = (N + 127) / 128;

    k_part<<<(E + CHUNK - 1) / CHUNK, 256, 0, stream>>>(ei, pfill, staged, E, NP);
    // build (NP blocks) || gemm layer 1 (gblocks)
    k_fat<<<NP + gblocks, 256, 0, stream>>>(staged, pfill, rowptr, csr, N, E, NP,
                                            u, W1, as1, ad1, hbuf, asv, adv);

    k_fused_agg<<<(N * 64 + 255) / 256, 256, 0, stream>>>(rowptr, csr, asv, adv, wedge, hbuf, b1, x2, N);

    // layer 2 (bf16 input)
    k_gemm3<__hip_bfloat16><<<gblocks, 256, 0, stream>>>(x2, W2, as2, ad2, hbuf, asv, adv, N);
    k_fused_agg<<<(N * 64 + 255) / 256, 256, 0, stream>>>(rowptr, csr, asv, adv, wedge, hbuf, b2, x2, N);

    k_pool<<<G, 1024, 0, stream>>>(x2, batchv, (float*)d_out, N);
}